// Round 1
// baseline (1068.735 us; speedup 1.0000x reference)
//
#include <hip/hip_runtime.h>
#include <cfloat>
#include <cstdint>

#define NROWS  4096
#define DIM    768
#define KCODES 65536

#define TM 128
#define TC 128
#define BK 64          // K-chunk (halves); 128-B LDS row stride (r3-verified swizzle geometry)
#define SA 40          // fallback path LDS stride
#define CAP 2048       // candidate list slots per row
#define DELTA 3.0e-4f  // guaranteed screening margin (worst-case err chain ~1.6e-4)

// workspace layout (bytes)
#define WS_ZSQ    0                          // 4096 f32
#define WS_RUNMIN 16384                      // 4096 u32
#define WS_CNT    32768                      // 4096 i32
#define WS_CODESI 49152                      // 4096 i32 (fallback)
#define WS_LOSS   65536                      // 1 f64
#define WS_LIST   131072                     // 4096*CAP i32 = 32 MB (fallback: keys u64)
#define WS_AH     (WS_LIST + (size_t)NROWS*CAP*4)
#define WS_BH     (WS_AH + (size_t)NROWS*DIM*2)
#define WS_NEED   (WS_BH + (size_t)KCODES*DIM*2)

typedef _Float16 half_t;
typedef _Float16 half4 __attribute__((ext_vector_type(4)));
typedef _Float16 half8 __attribute__((ext_vector_type(8)));
typedef float    f32x4 __attribute__((ext_vector_type(4)));

__device__ __forceinline__ void gld16(half_t* lds, const half_t* g) {
  __builtin_amdgcn_global_load_lds(
      (const __attribute__((address_space(1))) unsigned int*)g,
      (__attribute__((address_space(3))) unsigned int*)lds, 16, 0, 0);
}

// ---- k_convA: z -> fp16 hi, z_sq per row, init runmin/cnt, zero loss ------
__global__ void k_convA(const float* __restrict__ z, half_t* __restrict__ h,
                        float* __restrict__ zsq, unsigned int* __restrict__ runmin,
                        int* __restrict__ cnt, double* __restrict__ loss) {
  const int wave = threadIdx.x >> 6, lane = threadIdx.x & 63;
  const int row = blockIdx.x * 4 + wave;
  const float4* zr = (const float4*)(z + (size_t)row * DIM);
  half_t* hr = h + (size_t)row * DIM;
  float s = 0.f;
  #pragma unroll
  for (int p = 0; p < 3; ++p) {
    float4 v = zr[lane + p * 64];
    s = fmaf(v.x, v.x, s); s = fmaf(v.y, v.y, s);
    s = fmaf(v.z, v.z, s); s = fmaf(v.w, v.w, s);
    half4 hv = { (half_t)v.x, (half_t)v.y, (half_t)v.z, (half_t)v.w };
    *(half4*)(hr + (lane + p * 64) * 4) = hv;
  }
  #pragma unroll
  for (int off = 32; off; off >>= 1) s += __shfl_xor(s, off, 64);
  if (lane == 0) zsq[row] = s;
  const int gid = blockIdx.x * 256 + threadIdx.x;
  if (gid < NROWS) { runmin[gid] = 0x7f7fffffu; cnt[gid] = 0; }
  if (gid == 0) *loss = 0.0;
}

// ---- k_convB: cb -> fp16 hi, prescaled by 4096 ----------------------------
__global__ void k_convB(const float* __restrict__ src, half_t* __restrict__ h, int n8) {
  const int i = blockIdx.x * 256 + threadIdx.x;
  if (i >= n8) return;
  float4 v0 = ((const float4*)src)[2 * i];
  float4 v1 = ((const float4*)src)[2 * i + 1];
  float a[8] = {v0.x, v0.y, v0.z, v0.w, v1.x, v1.y, v1.z, v1.w};
  half8 hi;
  #pragma unroll
  for (int j = 0; j < 8; ++j) hi[j] = (half_t)(a[j] * 4096.f);
  ((half8*)h)[i] = hi;
}

// ---- k1_s1: 256x256-tile 8-phase fp16 MFMA screen + candidate collection --
// 512 threads = 8 waves (2 wm x 4 wn), per-wave output 128x64.
// Double-buffered K-tiles (BK=64), unit-granular staging, counted vmcnt gates
// at phases 4/8 only (T3+T4), setprio around MFMA (T5), r3 XOR swizzle (T2).
//
// LDS unit layout (unit-major, so each stage-unit is 128 contiguous lds rows):
//   A: lds_row = h*128 + wm*64 + (tm&3)*16 + r16   (h = tm>>2, m-half)
//   B: lds_row = g*128 + wn*32 + (tn&1)*16 + r16   (g = tn>>1, n-half)
// Per-row swizzle: physical 16B slot = logical ^ (lds_row & 7).
//
// Steady-state schedule per iter t (buf0 = tile 2t read p1-4, buf1 = 2t+1 read p5-8):
//   p1 (h0,g0): stage buf1.A1<-2t+1   p5 (h0,g0): stage buf0.A1<-2t+2
//   p2 (h0,g1): stage buf1.B0<-2t+1   p6 (h0,g1): stage buf0.B0<-2t+2
//   p3 (h1,g1): stage buf0.A0<-2t+2   p7 (h1,g1): stage buf1.A0<-2t+3
//   p4 (h1,g0): stage buf0.B1<-2t+2   p8 (h1,g0): stage buf1.B1<-2t+3
//   gates: vmcnt(4) at end of p4 and p8 (each unit = 2 loads; allow newest 2 units).
// Every unit has >=3 phases of flight; every overwrite is >=1 barrier after its
// last reader (deaths: A0@p2, B1@p3, A1@p4, B0@p4 within each buffer pass).

#define GATE4 asm volatile("s_waitcnt vmcnt(4)" ::: "memory")
#define GATE0 asm volatile("s_waitcnt vmcnt(0)" ::: "memory")
#define GATEN
#define NOSTAGE

#define STAGE_A(BUF, H, KD) { \
  _Pragma("unroll") \
  for (int i_ = 0; i_ < 2; ++i_) { \
    const int lr_ = (H) * 128 + i_ * 64 + wave * 8 + sr; \
    const int ar_ = i_ * 128 + (H) * 64 + wave * 8 + sr; \
    gld16(&sA[BUF][lr_ * 64 + ss * 8], Ag + (size_t)ar_ * DIM + (KD) + gsw8); \
  } }

#define STAGE_B(BUF, G, KD) { \
  _Pragma("unroll") \
  for (int i_ = 0; i_ < 2; ++i_) { \
    const int sub_ = i_ * 64 + wave * 8 + sr; \
    const int lr_ = (G) * 128 + sub_; \
    const int br_ = (sub_ >> 5) * 64 + (G) * 32 + (sub_ & 31); \
    gld16(&sB[BUF][lr_ * 64 + ss * 8], Bg + (size_t)br_ * DIM + (KD) + gsw8); \
  } }

#define PHASE_BODY(BUF, H, G, STAGE, GATE) { \
  half8 fa_[4][2], fb_[2][2]; \
  _Pragma("unroll") \
  for (int t4_ = 0; t4_ < 4; ++t4_) { \
    const int base_ = ((H) * 128 + wm * 64 + t4_ * 16 + l16) * 64; \
    fa_[t4_][0] = *(const half8*)&sA[BUF][base_ + (((0 * 4 + q) ^ (l16 & 7)) * 8)]; \
    fa_[t4_][1] = *(const half8*)&sA[BUF][base_ + (((1 * 4 + q) ^ (l16 & 7)) * 8)]; \
  } \
  _Pragma("unroll") \
  for (int t2_ = 0; t2_ < 2; ++t2_) { \
    const int base_ = ((G) * 128 + wn * 32 + t2_ * 16 + l16) * 64; \
    fb_[t2_][0] = *(const half8*)&sB[BUF][base_ + (((0 * 4 + q) ^ (l16 & 7)) * 8)]; \
    fb_[t2_][1] = *(const half8*)&sB[BUF][base_ + (((1 * 4 + q) ^ (l16 & 7)) * 8)]; \
  } \
  STAGE; \
  __builtin_amdgcn_s_barrier(); \
  __builtin_amdgcn_s_setprio(1); \
  _Pragma("unroll") \
  for (int t4_ = 0; t4_ < 4; ++t4_) { \
    _Pragma("unroll") \
    for (int t2_ = 0; t2_ < 2; ++t2_) { \
      const int ai_ = ((H) * 4 + t4_) * 4 + ((G) * 2 + t2_); \
      acc[ai_] = __builtin_amdgcn_mfma_f32_16x16x32_f16(fa_[t4_][0], fb_[t2_][0], acc[ai_], 0, 0, 0); \
      acc[ai_] = __builtin_amdgcn_mfma_f32_16x16x32_f16(fa_[t4_][1], fb_[t2_][1], acc[ai_], 0, 0, 0); \
    } } \
  __builtin_amdgcn_s_setprio(0); \
  GATE; \
  __builtin_amdgcn_s_barrier(); }

__global__ __launch_bounds__(512, 2) void k1_s1(
    const half_t* __restrict__ Ahg, const half_t* __restrict__ Bhg,
    const float* __restrict__ zsq, unsigned int* __restrict__ runmin,
    int* __restrict__ cnt, int* __restrict__ list) {
  __shared__ __align__(16) half_t sA[2][256 * 64];   // 64 KB
  __shared__ __align__(16) half_t sB[2][256 * 64];   // 64 KB
  __shared__ float lzs[256];
  __shared__ float redD[256][4];
  __shared__ float lbound[256];

  const int tid = threadIdx.x;
  const int row0  = blockIdx.x * 256;
  const int code0 = blockIdx.y * 256;
  const int wave = tid >> 6, lane = tid & 63;
  const int wm = wave >> 2, wn = wave & 3;
  const int q = lane >> 4, l16 = lane & 15;
  const int sr = lane >> 3, ss = lane & 7;
  const int gsw8 = (ss ^ sr) * 8;

  const half_t* Ag = Ahg + (size_t)row0 * DIM;
  const half_t* Bg = Bhg + (size_t)code0 * DIM;

  if (tid < 256) lzs[tid] = zsq[row0 + tid];

  f32x4 acc[32];
  #pragma unroll
  for (int i = 0; i < 32; ++i) acc[i] = (f32x4){0.f, 0.f, 0.f, 0.f};

  // prologue: buf0 <- tile0 (A0,B1,A1,B0), buf1 early units <- tile1 (A0,B1)
  STAGE_A(0, 0, 0);  STAGE_B(0, 1, 0);  STAGE_A(0, 1, 0);  STAGE_B(0, 0, 0);
  STAGE_A(1, 0, 64); STAGE_B(1, 1, 64);
  GATE4;                                        // buf0 fully landed (allow 2 buf1 units)
  asm volatile("s_waitcnt lgkmcnt(0)" ::: "memory");  // lzs ds_write visible
  __builtin_amdgcn_s_barrier();

  for (int t = 0; t < 5; ++t) {
    const int kdB  = t * 128 + 64;   // buf1 current tile (late units A1,B0)
    const int kdN0 = t * 128 + 128;  // buf0 next tile
    const int kdN1 = t * 128 + 192;  // buf1 next tile (early units A0,B1)
    PHASE_BODY(0, 0, 0, STAGE_A(1, 1, kdB),  GATEN);
    PHASE_BODY(0, 0, 1, STAGE_B(1, 0, kdB),  GATEN);
    PHASE_BODY(0, 1, 1, STAGE_A(0, 0, kdN0), GATEN);
    PHASE_BODY(0, 1, 0, STAGE_B(0, 1, kdN0), GATE4);
    PHASE_BODY(1, 0, 0, STAGE_A(0, 1, kdN0), GATEN);
    PHASE_BODY(1, 0, 1, STAGE_B(0, 0, kdN0), GATEN);
    PHASE_BODY(1, 1, 1, STAGE_A(1, 0, kdN1), GATEN);
    PHASE_BODY(1, 1, 0, STAGE_B(1, 1, kdN1), GATE4);
  }
  { // tail iter t=5: only tile-11 late units remain to stage
    PHASE_BODY(0, 0, 0, STAGE_A(1, 1, 704), GATEN);
    PHASE_BODY(0, 0, 1, STAGE_B(1, 0, 704), GATEN);
    PHASE_BODY(0, 1, 1, NOSTAGE, GATEN);
    PHASE_BODY(0, 1, 0, NOSTAGE, GATE0);
    PHASE_BODY(1, 0, 0, NOSTAGE, GATEN);
    PHASE_BODY(1, 0, 1, NOSTAGE, GATEN);
    PHASE_BODY(1, 1, 1, NOSTAGE, GATEN);
    PHASE_BODY(1, 1, 0, NOSTAGE, GATEN);
  }

  // transform acc -> approx distance d~ = fl(zs - 2^-11 * acc)
  const float c2 = -4.8828125e-4f;   // -2^-11 (B prescaled by 4096)
  #pragma unroll
  for (int tm = 0; tm < 8; ++tm)
    #pragma unroll
    for (int reg = 0; reg < 4; ++reg) {
      const float zs = lzs[wm * 128 + tm * 16 + q * 4 + reg];
      #pragma unroll
      for (int tn = 0; tn < 4; ++tn)
        acc[tm * 4 + tn][reg] = fmaf(c2, acc[tm * 4 + tn][reg], zs);
    }

  // block-local per-row min
  #pragma unroll
  for (int tm = 0; tm < 8; ++tm)
    #pragma unroll
    for (int reg = 0; reg < 4; ++reg) {
      float m = acc[tm * 4 + 0][reg];
      #pragma unroll
      for (int tn = 1; tn < 4; ++tn) m = fminf(m, acc[tm * 4 + tn][reg]);
      #pragma unroll
      for (int off = 8; off; off >>= 1) m = fminf(m, __shfl_xor(m, off, 64));
      if (l16 == 0) redD[wm * 128 + tm * 16 + q * 4 + reg][wn] = m;
    }
  __syncthreads();
  if (tid < 256) {
    const float lm = fminf(fminf(redD[tid][0], redD[tid][1]),
                           fminf(redD[tid][2], redD[tid][3]));
    const unsigned rg = runmin[row0 + tid];          // stale-safe: always >= true min
    atomicMin(&runmin[row0 + tid], __float_as_uint(lm));
    lbound[tid] = fminf(lm, __uint_as_float(rg)) + DELTA;
  }
  __syncthreads();

  // collect candidates within margin (provably includes reference winner + ties)
  #pragma unroll
  for (int tm = 0; tm < 8; ++tm)
    #pragma unroll
    for (int reg = 0; reg < 4; ++reg) {
      const int row_b = wm * 128 + tm * 16 + q * 4 + reg;
      const float b = lbound[row_b];
      #pragma unroll
      for (int tn = 0; tn < 4; ++tn) {
        const float d = acc[tm * 4 + tn][reg];
        if (d <= b) {
          const int grow = row0 + row_b;
          const int pos = atomicAdd(&cnt[grow], 1);
          if (pos < CAP) list[(size_t)grow * CAP + pos] = code0 + wn * 64 + tn * 16 + l16;
        }
      }
    }
}

// ---- k_refine: fp64 re-score of survivors + gather + STE + loss (fused) ---
__global__ void k_refine(const float* __restrict__ z, const float* __restrict__ cb,
                         const float* __restrict__ zsq, const int* __restrict__ cnt,
                         const int* __restrict__ list, float* __restrict__ out_codes,
                         float* __restrict__ outq, double* __restrict__ loss) {
  const int r = blockIdx.x;
  const int tid = threadIdx.x, wave = tid >> 6, lane = tid & 63;
  __shared__ unsigned long long wbest[4];
  __shared__ double wsum[4];
  __shared__ int sidx;
  __shared__ __align__(16) float zsh[DIM];

  if (tid < DIM / 4) ((float4*)zsh)[tid] = ((const float4*)(z + (size_t)r * DIM))[tid];
  __syncthreads();

  int n = cnt[r]; if (n > CAP) n = CAP;
  const bool empty = (n == 0); if (empty) n = 1;   // winner provably collected; guard anyway
  const double zsd = (double)zsq[r];
  unsigned long long best = ~0ull;
  for (int ci = wave; ci < n; ci += 4) {
    const int idx = empty ? 0 : list[(size_t)r * CAP + ci];
    const float4* cr = (const float4*)(cb + (size_t)idx * DIM);
    double s = 0.0;
    #pragma unroll
    for (int p = 0; p < 3; ++p) {
      const float4 cv = cr[lane + p * 64];
      const float4 zv = ((const float4*)zsh)[lane + p * 64];
      s += (double)zv.x * cv.x + (double)zv.y * cv.y +
           (double)zv.z * cv.z + (double)zv.w * cv.w;
    }
    #pragma unroll
    for (int off = 32; off; off >>= 1) s += __shfl_xor(s, off, 64);
    const float d = (float)(zsd - 2.0 * s);        // single rounding, ref semantics
    const unsigned long long key =
        ((unsigned long long)__float_as_uint(d) << 32) | (unsigned)idx;
    if (key < best) best = key;                    // (d, idx) lexicographic
  }
  if (lane == 0) wbest[wave] = best;
  __syncthreads();
  if (tid == 0) {
    unsigned long long b = wbest[0];
    #pragma unroll
    for (int w = 1; w < 4; ++w) if (wbest[w] < b) b = wbest[w];
    const int idx = (int)(unsigned)(b & 0xffffffffull);
    sidx = idx;
    out_codes[r] = (float)idx;
  }
  __syncthreads();

  const int c = sidx;
  double ls = 0.0;
  #pragma unroll
  for (int j = 0; j < 3; ++j) {
    const int e = tid + j * 256;
    const float qx = cb[(size_t)c * DIM + e];
    const float zx = zsh[e];
    const float dd = qx - zx;
    outq[(size_t)r * DIM + e] = zx + dd;           // fl(z + fl(q-z)) bitwise
    ls += (double)dd * (double)dd;
  }
  #pragma unroll
  for (int off = 32; off; off >>= 1) ls += __shfl_xor(ls, off, 64);
  if (lane == 0) wsum[wave] = ls;
  __syncthreads();
  if (tid == 0) atomicAdd(loss, wsum[0] + wsum[1] + wsum[2] + wsum[3]);
}

// ---- k4: finalize loss -----------------------------------------------------
__global__ void k4_final(const double* __restrict__ loss, float* __restrict__ out) {
  float m = (float)(*loss / ((double)NROWS * (double)DIM));
  out[0] = m + 0.25f * m;
}

// ======================= fallback path (ws too small) =======================
__global__ void k0_zsq(const float* __restrict__ z, float* __restrict__ zsq,
                       unsigned long long* __restrict__ keys, double* __restrict__ loss) {
  const int wave = threadIdx.x >> 6, lane = threadIdx.x & 63;
  const int row = blockIdx.x * 4 + wave;
  const float* zr = z + (size_t)row * DIM;
  float s = 0.f;
  #pragma unroll
  for (int i = 0; i < DIM / 64; ++i) { float v = zr[lane + i * 64]; s = fmaf(v, v, s); }
  #pragma unroll
  for (int off = 32; off; off >>= 1) s += __shfl_xor(s, off, 64);
  if (lane == 0) zsq[row] = s;
  const int gid = blockIdx.x * 256 + threadIdx.x;
  if (gid < NROWS) keys[gid] = ~0ull;
  if (gid == 0) *loss = 0.0;
}

__global__ __launch_bounds__(256, 2) void k1_mfma(
    const float* __restrict__ z, const float* __restrict__ cb,
    const float* __restrict__ zsq, unsigned long long* __restrict__ keys) {
  __shared__ half_t Ah[TM * SA], Al[TM * SA], Bh[TC * SA], Bl[TC * SA];
  __shared__ float lzs[TM];
  __shared__ float redD[TM][2];
  __shared__ int   redI[TM][2];

  const int tid  = threadIdx.x;
  const int row0  = blockIdx.x * TM;
  const int code0 = blockIdx.y * TC;
  const int wave = tid >> 6, lane = tid & 63;
  const int wm = wave & 1, wn = wave >> 1;
  const int q = lane >> 4, l16 = lane & 15;

  if (tid < TM) lzs[tid] = zsq[row0 + tid];

  const int srow = tid >> 2;
  const int sko  = (tid & 3) * 8;

  f32x4 acc0[16], acc1[16];
  #pragma unroll
  for (int i = 0; i < 16; ++i) {
    acc0[i] = (f32x4){0.f, 0.f, 0.f, 0.f};
    acc1[i] = (f32x4){0.f, 0.f, 0.f, 0.f};
  }

  const float* zp = z  + (size_t)row0  * DIM;
  const float* bp = cb + (size_t)code0 * DIM;

  for (int kd = 0; kd < DIM; kd += 32) {
    __syncthreads();
    #pragma unroll
    for (int s = 0; s < 2; ++s) {
      const int r = srow + s * 64;
      const float* srca = zp + (size_t)r * DIM + kd + sko;
      float4 v0 = *(const float4*)srca;
      float4 v1 = *(const float4*)(srca + 4);
      float a[8] = {v0.x, v0.y, v0.z, v0.w, v1.x, v1.y, v1.z, v1.w};
      half8 hi, lo;
      #pragma unroll
      for (int j = 0; j < 8; ++j) {
        half_t h = (half_t)a[j];
        hi[j] = h;
        lo[j] = (half_t)((a[j] - (float)h) * 4096.f);
      }
      *(half8*)&Ah[r * SA + sko] = hi;
      *(half8*)&Al[r * SA + sko] = lo;
      const float* srcb = bp + (size_t)r * DIM + kd + sko;
      v0 = *(const float4*)srcb; v1 = *(const float4*)(srcb + 4);
      float b[8] = {v0.x, v0.y, v0.z, v0.w, v1.x, v1.y, v1.z, v1.w};
      #pragma unroll
      for (int j = 0; j < 8; ++j) {
        float bs = b[j] * 4096.f;
        half_t h = (half_t)bs;
        hi[j] = h;
        lo[j] = (half_t)((bs - (float)h) * 4096.f);
      }
      *(half8*)&Bh[r * SA + sko] = hi;
      *(half8*)&Bl[r * SA + sko] = lo;
    }
    __syncthreads();

    half8 fa_h[4], fa_l[4], fb_h[4], fb_l[4];
    #pragma unroll
    for (int t = 0; t < 4; ++t) {
      const int ar = (wm * 64 + t * 16 + l16) * SA + q * 8;
      fa_h[t] = *(const half8*)&Ah[ar];
      fa_l[t] = *(const half8*)&Al[ar];
      const int br = (wn * 64 + t * 16 + l16) * SA + q * 8;
      fb_h[t] = *(const half8*)&Bh[br];
      fb_l[t] = *(const half8*)&Bl[br];
    }
    #pragma unroll
    for (int tm = 0; tm < 4; ++tm)
      #pragma unroll
      for (int tn = 0; tn < 4; ++tn) {
        const int i = tm * 4 + tn;
        acc0[i] = __builtin_amdgcn_mfma_f32_16x16x32_f16(fa_h[tm], fb_h[tn], acc0[i], 0, 0, 0);
        acc1[i] = __builtin_amdgcn_mfma_f32_16x16x32_f16(fa_l[tm], fb_h[tn], acc1[i], 0, 0, 0);
        acc1[i] = __builtin_amdgcn_mfma_f32_16x16x32_f16(fa_h[tm], fb_l[tn], acc1[i], 0, 0, 0);
      }
  }

  const float c1 = 2.44140625e-4f;
  const float c2 = -4.8828125e-4f;
  #pragma unroll
  for (int tm = 0; tm < 4; ++tm) {
    #pragma unroll
    for (int reg = 0; reg < 4; ++reg) {
      const int row_b = wm * 64 + tm * 16 + q * 4 + reg;
      const float zs = lzs[row_b];
      float bd = FLT_MAX; int bi = 0x7fffffff;
      #pragma unroll
      for (int tn = 0; tn < 4; ++tn) {
        const int i = tm * 4 + tn;
        float v = fmaf(c1, acc1[i][reg], acc0[i][reg]);
        float d = fmaf(c2, v, zs);
        const int ci = code0 + wn * 64 + tn * 16 + l16;
        if (d < bd || (d == bd && ci < bi)) { bd = d; bi = ci; }
      }
      #pragma unroll
      for (int off = 8; off; off >>= 1) {
        float od = __shfl_xor(bd, off, 64);
        int   oi = __shfl_xor(bi, off, 64);
        if (od < bd || (od == bd && oi < bi)) { bd = od; bi = oi; }
      }
      if (l16 == 0) { redD[row_b][wn] = bd; redI[row_b][wn] = bi; }
    }
  }
  __syncthreads();
  if (tid < TM) {
    float d0 = redD[tid][0]; int i0 = redI[tid][0];
    float d1 = redD[tid][1]; int i1 = redI[tid][1];
    if (d1 < d0 || (d1 == d0 && i1 < i0)) { d0 = d1; i0 = i1; }
    unsigned long long key = ((unsigned long long)__float_as_uint(d0) << 32) | (unsigned int)i0;
    atomicMin(&keys[row0 + tid], key);
  }
}

__global__ void k2_codes(const unsigned long long* __restrict__ keys,
                         float* __restrict__ out_codes, int* __restrict__ codes_i) {
  const int r = blockIdx.x * 256 + threadIdx.x;
  const int idx = (int)(unsigned int)(keys[r] & 0xffffffffull);
  out_codes[r] = (float)idx;
  codes_i[r] = idx;
}

__global__ void k3_quant_loss(const float* __restrict__ z, const float* __restrict__ cb,
                              const int* __restrict__ codes, float* __restrict__ outq,
                              double* __restrict__ loss) {
  const int gid = blockIdx.x * blockDim.x + threadIdx.x;
  const int e0 = gid * 4;
  const int row = e0 / DIM;
  const int col = e0 - row * DIM;
  const int c = codes[row];
  const float4 zv = *(const float4*)(z + e0);
  const float4 qv = *(const float4*)(cb + (size_t)c * DIM + col);
  float d0 = qv.x - zv.x, d1 = qv.y - zv.y, d2 = qv.z - zv.z, d3 = qv.w - zv.w;
  float4 ov = { zv.x + d0, zv.y + d1, zv.z + d2, zv.w + d3 };
  *(float4*)(outq + e0) = ov;
  double s = (double)(d0 * d0) + (double)(d1 * d1) + (double)(d2 * d2) + (double)(d3 * d3);
  #pragma unroll
  for (int off = 32; off; off >>= 1) s += __shfl_xor(s, off, 64);
  __shared__ double wsum[4];
  const int wave = threadIdx.x >> 6, lane = threadIdx.x & 63;
  if (lane == 0) wsum[wave] = s;
  __syncthreads();
  if (threadIdx.x == 0) atomicAdd(loss, wsum[0] + wsum[1] + wsum[2] + wsum[3]);
}

extern "C" void kernel_launch(void* const* d_in, const int* in_sizes, int n_in,
                              void* d_out, int out_size, void* d_ws, size_t ws_size,
                              hipStream_t stream) {
  const float* z  = (const float*)d_in[0];
  const float* cb = (const float*)d_in[1];
  float* out = (float*)d_out;          // [codes 4096][q_ste 3145728][loss 1]
  char* ws = (char*)d_ws;
  float*  zsq = (float*)(ws + WS_ZSQ);
  unsigned int* runmin = (unsigned int*)(ws + WS_RUNMIN);
  int* cnt     = (int*)(ws + WS_CNT);
  int* codes_i = (int*)(ws + WS_CODESI);
  double* loss = (double*)(ws + WS_LOSS);
  int* list    = (int*)(ws + WS_LIST);
  unsigned long long* keys = (unsigned long long*)(ws + WS_LIST);

  if (ws_size >= WS_NEED) {
    half_t* Ahg = (half_t*)(ws + WS_AH);
    half_t* Bhg = (half_t*)(ws + WS_BH);
    dim3 g1s(NROWS / 256, KCODES / 256);
    k_convA<<<NROWS / 4, 256, 0, stream>>>(z, Ahg, zsq, runmin, cnt, loss);
    k_convB<<<(KCODES * DIM / 8 + 255) / 256, 256, 0, stream>>>(cb, Bhg, KCODES * DIM / 8);
    k1_s1<<<g1s, 512, 0, stream>>>(Ahg, Bhg, zsq, runmin, cnt, list);
    k_refine<<<NROWS, 256, 0, stream>>>(z, cb, zsq, cnt, list, out, out + NROWS, loss);
  } else {
    dim3 g1(NROWS / TM, KCODES / TC);
    k0_zsq<<<NROWS / 4, 256, 0, stream>>>(z, zsq, keys, loss);
    k1_mfma<<<g1, 256, 0, stream>>>(z, cb, zsq, keys);
    k2_codes<<<NROWS / 256, 256, 0, stream>>>(keys, out, codes_i);
    k3_quant_loss<<<(NROWS * DIM / 4) / 256, 256, 0, stream>>>(z, cb, codes_i, out + NROWS, loss);
  }

  k4_final<<<1, 1, 0, stream>>>(loss, out + NROWS + (size_t)NROWS * DIM);
}

// Round 2
// 1000.212 us; speedup vs baseline: 1.0685x; 1.0685x over previous
//
#include <hip/hip_runtime.h>
#include <cfloat>
#include <cstdint>

#define NROWS  4096
#define DIM    768
#define KCODES 65536

#define TM 128
#define TC 128
#define BK 64          // K-chunk (halves); 128-B LDS row stride (r3-verified swizzle geometry)
#define SA 40          // fallback path LDS stride
#define CAP 2048       // candidate list slots per row
#define DELTA 3.0e-4f  // guaranteed screening margin (worst-case err chain ~1.6e-4)

// workspace layout (bytes)
#define WS_ZSQ    0                          // 4096 f32
#define WS_RUNMIN 16384                      // 4096 u32
#define WS_CNT    32768                      // 4096 i32
#define WS_CODESI 49152                      // 4096 i32 (fallback)
#define WS_LOSS   65536                      // 1 f64
#define WS_LIST   131072                     // 4096*CAP i32 = 32 MB (fallback: keys u64)
#define WS_AH     (WS_LIST + (size_t)NROWS*CAP*4)
#define WS_BH     (WS_AH + (size_t)NROWS*DIM*2)
#define WS_NEED   (WS_BH + (size_t)KCODES*DIM*2)

typedef _Float16 half_t;
typedef _Float16 half4 __attribute__((ext_vector_type(4)));
typedef _Float16 half8 __attribute__((ext_vector_type(8)));
typedef float    f32x4 __attribute__((ext_vector_type(4)));
typedef unsigned int uint;
typedef __attribute__((address_space(3))) half_t lds_half_t;

__device__ __forceinline__ void gld16(half_t* lds, const half_t* g) {
  __builtin_amdgcn_global_load_lds(
      (const __attribute__((address_space(1))) unsigned int*)g,
      (__attribute__((address_space(3))) unsigned int*)lds, 16, 0, 0);
}

// ---- k_convA: z -> fp16 hi, z_sq per row, init runmin/cnt, zero loss ------
__global__ void k_convA(const float* __restrict__ z, half_t* __restrict__ h,
                        float* __restrict__ zsq, unsigned int* __restrict__ runmin,
                        int* __restrict__ cnt, double* __restrict__ loss) {
  const int wave = threadIdx.x >> 6, lane = threadIdx.x & 63;
  const int row = blockIdx.x * 4 + wave;
  const float4* zr = (const float4*)(z + (size_t)row * DIM);
  half_t* hr = h + (size_t)row * DIM;
  float s = 0.f;
  #pragma unroll
  for (int p = 0; p < 3; ++p) {
    float4 v = zr[lane + p * 64];
    s = fmaf(v.x, v.x, s); s = fmaf(v.y, v.y, s);
    s = fmaf(v.z, v.z, s); s = fmaf(v.w, v.w, s);
    half4 hv = { (half_t)v.x, (half_t)v.y, (half_t)v.z, (half_t)v.w };
    *(half4*)(hr + (lane + p * 64) * 4) = hv;
  }
  #pragma unroll
  for (int off = 32; off; off >>= 1) s += __shfl_xor(s, off, 64);
  if (lane == 0) zsq[row] = s;
  const int gid = blockIdx.x * 256 + threadIdx.x;
  if (gid < NROWS) { runmin[gid] = 0x7f7fffffu; cnt[gid] = 0; }
  if (gid == 0) *loss = 0.0;
}

// ---- k_convB: cb -> fp16 hi, prescaled by 4096 ----------------------------
__global__ void k_convB(const float* __restrict__ src, half_t* __restrict__ h, int n8) {
  const int i = blockIdx.x * 256 + threadIdx.x;
  if (i >= n8) return;
  float4 v0 = ((const float4*)src)[2 * i];
  float4 v1 = ((const float4*)src)[2 * i + 1];
  float a[8] = {v0.x, v0.y, v0.z, v0.w, v1.x, v1.y, v1.z, v1.w};
  half8 hi;
  #pragma unroll
  for (int j = 0; j < 8; ++j) hi[j] = (half_t)(a[j] * 4096.f);
  ((half8*)h)[i] = hi;
}

// ---- k1_s1: 256x256-tile 8-phase fp16 MFMA screen + candidate collection --
// 512 threads = 8 waves (2 wm x 4 wn), per-wave output 128x64.
// v2: IDENTICAL schedule/swizzle/gates to v1 (verified absmax=0), but the
// phase body is re-expressed so the compiler cannot serialize it:
//   - 12 ds_read_b128 as inline asm (opaque to waitcnt insertion -> no
//     compiler-inserted vmcnt drains per phase) with immediate offsets off
//     8 precomputed per-thread base registers (zero per-phase addr VALU)
//   - barrier -> lgkmcnt(0) -> sched_barrier(0) (rule #18) -> 16 MFMA with
//     literal acc indices (no arrays, no runtime indexing -> no scratch)
//   - staging bases hoisted; per-call-site offsets are compile-time consts.
//
// Steady-state schedule per iter t (buf0 = tile 2t read p1-4, buf1 = 2t+1 read p5-8):
//   p1 (h0,g0): stage buf1.A1<-2t+1   p5 (h0,g0): stage buf0.A1<-2t+2
//   p2 (h0,g1): stage buf1.B0<-2t+1   p6 (h0,g1): stage buf0.B0<-2t+2
//   p3 (h1,g1): stage buf0.A0<-2t+2   p7 (h1,g1): stage buf1.A0<-2t+3
//   p4 (h1,g0): stage buf0.B1<-2t+2   p8 (h1,g0): stage buf1.B1<-2t+3
//   gates: vmcnt(4) at end of p4 and p8 (each unit = 2 loads/thread).

#define GATE4 asm volatile("s_waitcnt vmcnt(4)" ::: "memory")
#define GATE0 asm volatile("s_waitcnt vmcnt(0)" ::: "memory")
#define GATEN
#define NOSTAGE

#define DSR(dst, base, imm) \
  asm volatile("ds_read_b128 %0, %1 offset:%2" : "=v"(dst) : "v"(base), "n"(imm))

#define MFMA2(AI, Ax0, Ax1, Bx0, Bx1) \
  acc[AI] = __builtin_amdgcn_mfma_f32_16x16x32_f16(Ax0, Bx0, acc[AI], 0, 0, 0); \
  acc[AI] = __builtin_amdgcn_mfma_f32_16x16x32_f16(Ax1, Bx1, acc[AI], 0, 0, 0)

#define STAGE_A(BUF, H, KD) { \
  gld16(stA + (BUF)*16384 + ((H)*128 +  0)*64, gAbase + (size_t)(((H)*64 +   0)*DIM) + (KD)); \
  gld16(stA + (BUF)*16384 + ((H)*128 + 64)*64, gAbase + (size_t)(((H)*64 + 128)*DIM) + (KD)); }

#define STAGE_B(BUF, G, KD) { \
  gld16(stB + (BUF)*16384 + ((G)*128 +  0)*64, gBbase + (size_t)(((G)*32 +   0)*DIM) + (KD)); \
  gld16(stB + (BUF)*16384 + ((G)*128 + 64)*64, gBbase + (size_t)(((G)*32 + 128)*DIM) + (KD)); }

#define PHASE_BODY(BUF, H, G, STAGE, GATE) { \
  half8 a00, a10, a20, a30, a01, a11, a21, a31, b00, b10, b01, b11; \
  DSR(a00, rA##BUF##0, (H)*16384 + 0); \
  DSR(a10, rA##BUF##0, (H)*16384 + 2048); \
  DSR(a20, rA##BUF##0, (H)*16384 + 4096); \
  DSR(a30, rA##BUF##0, (H)*16384 + 6144); \
  DSR(a01, rA##BUF##1, (H)*16384 + 0); \
  DSR(a11, rA##BUF##1, (H)*16384 + 2048); \
  DSR(a21, rA##BUF##1, (H)*16384 + 4096); \
  DSR(a31, rA##BUF##1, (H)*16384 + 6144); \
  DSR(b00, rB##BUF##0, (G)*16384 + 0); \
  DSR(b10, rB##BUF##0, (G)*16384 + 2048); \
  DSR(b01, rB##BUF##1, (G)*16384 + 0); \
  DSR(b11, rB##BUF##1, (G)*16384 + 2048); \
  STAGE; \
  __builtin_amdgcn_s_barrier(); \
  asm volatile("s_waitcnt lgkmcnt(0)" ::: "memory"); \
  __builtin_amdgcn_sched_barrier(0); \
  __builtin_amdgcn_s_setprio(1); \
  MFMA2(((H)*4+0)*4 + (G)*2 + 0, a00, a01, b00, b01); \
  MFMA2(((H)*4+0)*4 + (G)*2 + 1, a00, a01, b10, b11); \
  MFMA2(((H)*4+1)*4 + (G)*2 + 0, a10, a11, b00, b01); \
  MFMA2(((H)*4+1)*4 + (G)*2 + 1, a10, a11, b10, b11); \
  MFMA2(((H)*4+2)*4 + (G)*2 + 0, a20, a21, b00, b01); \
  MFMA2(((H)*4+2)*4 + (G)*2 + 1, a20, a21, b10, b11); \
  MFMA2(((H)*4+3)*4 + (G)*2 + 0, a30, a31, b00, b01); \
  MFMA2(((H)*4+3)*4 + (G)*2 + 1, a30, a31, b10, b11); \
  __builtin_amdgcn_s_setprio(0); \
  GATE; \
  __builtin_amdgcn_s_barrier(); }

__global__ __launch_bounds__(512, 2) void k1_s1(
    const half_t* __restrict__ Ahg, const half_t* __restrict__ Bhg,
    const float* __restrict__ zsq, unsigned int* __restrict__ runmin,
    int* __restrict__ cnt, int* __restrict__ list) {
  __shared__ __align__(16) half_t sA[2][256 * 64];   // 64 KB
  __shared__ __align__(16) half_t sB[2][256 * 64];   // 64 KB
  __shared__ float lzs[256];
  __shared__ float redD[256][4];
  __shared__ float lbound[256];

  const int tid = threadIdx.x;
  const int row0  = blockIdx.x * 256;
  const int code0 = blockIdx.y * 256;
  const int wave = tid >> 6, lane = tid & 63;
  const int wm = wave >> 2, wn = wave & 3;
  const int q = lane >> 4, l16 = lane & 15;
  const int sr = lane >> 3, ss = lane & 7;
  const int gsw8 = (ss ^ sr) * 8;
  const int s0 = wave * 8 + sr;                    // staging sub-row 0..63

  if (tid < 256) lzs[tid] = zsq[row0 + tid];

  // ---- hoisted LDS read bases (bytes, as3 addresses) ----
  const uint ldsA = (uint)(size_t)(lds_half_t*)&sA[0][0];
  const uint ldsB = (uint)(size_t)(lds_half_t*)&sB[0][0];
  const int xr = l16 & 7;
  const uint rA00 = ldsA + (uint)((wm * 64 + l16) * 128 + ((q ^ xr) * 16));
  const uint rA01 = ldsA + (uint)((wm * 64 + l16) * 128 + (((4 + q) ^ xr) * 16));
  const uint rA10 = rA00 + 32768u;
  const uint rA11 = rA01 + 32768u;
  const uint rB00 = ldsB + (uint)((wn * 32 + l16) * 128 + ((q ^ xr) * 16));
  const uint rB01 = ldsB + (uint)((wn * 32 + l16) * 128 + (((4 + q) ^ xr) * 16));
  const uint rB10 = rB00 + 32768u;
  const uint rB11 = rB01 + 32768u;

  // ---- hoisted staging bases ----
  half_t* stA = &sA[0][0] + s0 * 64 + ss * 8;
  half_t* stB = &sB[0][0] + s0 * 64 + ss * 8;
  const half_t* gAbase = Ahg + (size_t)(row0 + s0) * DIM + gsw8;
  const half_t* gBbase = Bhg + (size_t)(code0 + (s0 >> 5) * 64 + (s0 & 31)) * DIM + gsw8;

  f32x4 acc[32];
  #pragma unroll
  for (int i = 0; i < 32; ++i) acc[i] = (f32x4){0.f, 0.f, 0.f, 0.f};

  // prologue: buf0 <- tile0 (A0,B1,A1,B0), buf1 early units <- tile1 (A0,B1)
  STAGE_A(0, 0, 0);  STAGE_B(0, 1, 0);  STAGE_A(0, 1, 0);  STAGE_B(0, 0, 0);
  STAGE_A(1, 0, 64); STAGE_B(1, 1, 64);
  GATE4;                                        // buf0 fully landed (allow 2 buf1 units)
  asm volatile("s_waitcnt lgkmcnt(0)" ::: "memory");  // lzs ds_write visible
  __builtin_amdgcn_s_barrier();

  for (int t = 0; t < 5; ++t) {
    const int kdB  = t * 128 + 64;   // buf1 current tile (late units A1,B0)
    const int kdN0 = t * 128 + 128;  // buf0 next tile
    const int kdN1 = t * 128 + 192;  // buf1 next tile (early units A0,B1)
    PHASE_BODY(0, 0, 0, STAGE_A(1, 1, kdB),  GATEN);
    PHASE_BODY(0, 0, 1, STAGE_B(1, 0, kdB),  GATEN);
    PHASE_BODY(0, 1, 1, STAGE_A(0, 0, kdN0), GATEN);
    PHASE_BODY(0, 1, 0, STAGE_B(0, 1, kdN0), GATE4);
    PHASE_BODY(1, 0, 0, STAGE_A(0, 1, kdN0), GATEN);
    PHASE_BODY(1, 0, 1, STAGE_B(0, 0, kdN0), GATEN);
    PHASE_BODY(1, 1, 1, STAGE_A(1, 0, kdN1), GATEN);
    PHASE_BODY(1, 1, 0, STAGE_B(1, 1, kdN1), GATE4);
  }
  { // tail iter t=5: only tile-11 late units remain to stage
    PHASE_BODY(0, 0, 0, STAGE_A(1, 1, 704), GATEN);
    PHASE_BODY(0, 0, 1, STAGE_B(1, 0, 704), GATEN);
    PHASE_BODY(0, 1, 1, NOSTAGE, GATEN);
    PHASE_BODY(0, 1, 0, NOSTAGE, GATE0);
    PHASE_BODY(1, 0, 0, NOSTAGE, GATEN);
    PHASE_BODY(1, 0, 1, NOSTAGE, GATEN);
    PHASE_BODY(1, 1, 1, NOSTAGE, GATEN);
    PHASE_BODY(1, 1, 0, NOSTAGE, GATEN);
  }

  // transform acc -> approx distance d~ = fl(zs - 2^-11 * acc)
  const float c2 = -4.8828125e-4f;   // -2^-11 (B prescaled by 4096)
  #pragma unroll
  for (int tm = 0; tm < 8; ++tm)
    #pragma unroll
    for (int reg = 0; reg < 4; ++reg) {
      const float zs = lzs[wm * 128 + tm * 16 + q * 4 + reg];
      #pragma unroll
      for (int tn = 0; tn < 4; ++tn)
        acc[tm * 4 + tn][reg] = fmaf(c2, acc[tm * 4 + tn][reg], zs);
    }

  // block-local per-row min
  #pragma unroll
  for (int tm = 0; tm < 8; ++tm)
    #pragma unroll
    for (int reg = 0; reg < 4; ++reg) {
      float m = acc[tm * 4 + 0][reg];
      #pragma unroll
      for (int tn = 1; tn < 4; ++tn) m = fminf(m, acc[tm * 4 + tn][reg]);
      #pragma unroll
      for (int off = 8; off; off >>= 1) m = fminf(m, __shfl_xor(m, off, 64));
      if (l16 == 0) redD[wm * 128 + tm * 16 + q * 4 + reg][wn] = m;
    }
  __syncthreads();
  if (tid < 256) {
    const float lm = fminf(fminf(redD[tid][0], redD[tid][1]),
                           fminf(redD[tid][2], redD[tid][3]));
    const unsigned rg = runmin[row0 + tid];          // stale-safe: always >= true min
    atomicMin(&runmin[row0 + tid], __float_as_uint(lm));
    lbound[tid] = fminf(lm, __uint_as_float(rg)) + DELTA;
  }
  __syncthreads();

  // collect candidates within margin (provably includes reference winner + ties)
  #pragma unroll
  for (int tm = 0; tm < 8; ++tm)
    #pragma unroll
    for (int reg = 0; reg < 4; ++reg) {
      const int row_b = wm * 128 + tm * 16 + q * 4 + reg;
      const float b = lbound[row_b];
      #pragma unroll
      for (int tn = 0; tn < 4; ++tn) {
        const float d = acc[tm * 4 + tn][reg];
        if (d <= b) {
          const int grow = row0 + row_b;
          const int pos = atomicAdd(&cnt[grow], 1);
          if (pos < CAP) list[(size_t)grow * CAP + pos] = code0 + wn * 64 + tn * 16 + l16;
        }
      }
    }
}

// ---- k_refine: fp64 re-score of survivors + gather + STE + loss (fused) ---
__global__ void k_refine(const float* __restrict__ z, const float* __restrict__ cb,
                         const float* __restrict__ zsq, const int* __restrict__ cnt,
                         const int* __restrict__ list, float* __restrict__ out_codes,
                         float* __restrict__ outq, double* __restrict__ loss) {
  const int r = blockIdx.x;
  const int tid = threadIdx.x, wave = tid >> 6, lane = tid & 63;
  __shared__ unsigned long long wbest[4];
  __shared__ double wsum[4];
  __shared__ int sidx;
  __shared__ __align__(16) float zsh[DIM];

  if (tid < DIM / 4) ((float4*)zsh)[tid] = ((const float4*)(z + (size_t)r * DIM))[tid];
  __syncthreads();

  int n = cnt[r]; if (n > CAP) n = CAP;
  const bool empty = (n == 0); if (empty) n = 1;   // winner provably collected; guard anyway
  const double zsd = (double)zsq[r];
  unsigned long long best = ~0ull;
  for (int ci = wave; ci < n; ci += 4) {
    const int idx = empty ? 0 : list[(size_t)r * CAP + ci];
    const float4* cr = (const float4*)(cb + (size_t)idx * DIM);
    double s = 0.0;
    #pragma unroll
    for (int p = 0; p < 3; ++p) {
      const float4 cv = cr[lane + p * 64];
      const float4 zv = ((const float4*)zsh)[lane + p * 64];
      s += (double)zv.x * cv.x + (double)zv.y * cv.y +
           (double)zv.z * cv.z + (double)zv.w * cv.w;
    }
    #pragma unroll
    for (int off = 32; off; off >>= 1) s += __shfl_xor(s, off, 64);
    const float d = (float)(zsd - 2.0 * s);        // single rounding, ref semantics
    const unsigned long long key =
        ((unsigned long long)__float_as_uint(d) << 32) | (unsigned)idx;
    if (key < best) best = key;                    // (d, idx) lexicographic
  }
  if (lane == 0) wbest[wave] = best;
  __syncthreads();
  if (tid == 0) {
    unsigned long long b = wbest[0];
    #pragma unroll
    for (int w = 1; w < 4; ++w) if (wbest[w] < b) b = wbest[w];
    const int idx = (int)(unsigned)(b & 0xffffffffull);
    sidx = idx;
    out_codes[r] = (float)idx;
  }
  __syncthreads();

  const int c = sidx;
  double ls = 0.0;
  #pragma unroll
  for (int j = 0; j < 3; ++j) {
    const int e = tid + j * 256;
    const float qx = cb[(size_t)c * DIM + e];
    const float zx = zsh[e];
    const float dd = qx - zx;
    outq[(size_t)r * DIM + e] = zx + dd;           // fl(z + fl(q-z)) bitwise
    ls += (double)dd * (double)dd;
  }
  #pragma unroll
  for (int off = 32; off; off >>= 1) ls += __shfl_xor(ls, off, 64);
  if (lane == 0) wsum[wave] = ls;
  __syncthreads();
  if (tid == 0) atomicAdd(loss, wsum[0] + wsum[1] + wsum[2] + wsum[3]);
}

// ---- k4: finalize loss -----------------------------------------------------
__global__ void k4_final(const double* __restrict__ loss, float* __restrict__ out) {
  float m = (float)(*loss / ((double)NROWS * (double)DIM));
  out[0] = m + 0.25f * m;
}

// ======================= fallback path (ws too small) =======================
__global__ void k0_zsq(const float* __restrict__ z, float* __restrict__ zsq,
                       unsigned long long* __restrict__ keys, double* __restrict__ loss) {
  const int wave = threadIdx.x >> 6, lane = threadIdx.x & 63;
  const int row = blockIdx.x * 4 + wave;
  const float* zr = z + (size_t)row * DIM;
  float s = 0.f;
  #pragma unroll
  for (int i = 0; i < DIM / 64; ++i) { float v = zr[lane + i * 64]; s = fmaf(v, v, s); }
  #pragma unroll
  for (int off = 32; off; off >>= 1) s += __shfl_xor(s, off, 64);
  if (lane == 0) zsq[row] = s;
  const int gid = blockIdx.x * 256 + threadIdx.x;
  if (gid < NROWS) keys[gid] = ~0ull;
  if (gid == 0) *loss = 0.0;
}

__global__ __launch_bounds__(256, 2) void k1_mfma(
    const float* __restrict__ z, const float* __restrict__ cb,
    const float* __restrict__ zsq, unsigned long long* __restrict__ keys) {
  __shared__ half_t Ah[TM * SA], Al[TM * SA], Bh[TC * SA], Bl[TC * SA];
  __shared__ float lzs[TM];
  __shared__ float redD[TM][2];
  __shared__ int   redI[TM][2];

  const int tid  = threadIdx.x;
  const int row0  = blockIdx.x * TM;
  const int code0 = blockIdx.y * TC;
  const int wave = tid >> 6, lane = tid & 63;
  const int wm = wave & 1, wn = wave >> 1;
  const int q = lane >> 4, l16 = lane & 15;

  if (tid < TM) lzs[tid] = zsq[row0 + tid];

  const int srow = tid >> 2;
  const int sko  = (tid & 3) * 8;

  f32x4 acc0[16], acc1[16];
  #pragma unroll
  for (int i = 0; i < 16; ++i) {
    acc0[i] = (f32x4){0.f, 0.f, 0.f, 0.f};
    acc1[i] = (f32x4){0.f, 0.f, 0.f, 0.f};
  }

  const float* zp = z  + (size_t)row0  * DIM;
  const float* bp = cb + (size_t)code0 * DIM;

  for (int kd = 0; kd < DIM; kd += 32) {
    __syncthreads();
    #pragma unroll
    for (int s = 0; s < 2; ++s) {
      const int r = srow + s * 64;
      const float* srca = zp + (size_t)r * DIM + kd + sko;
      float4 v0 = *(const float4*)srca;
      float4 v1 = *(const float4*)(srca + 4);
      float a[8] = {v0.x, v0.y, v0.z, v0.w, v1.x, v1.y, v1.z, v1.w};
      half8 hi, lo;
      #pragma unroll
      for (int j = 0; j < 8; ++j) {
        half_t h = (half_t)a[j];
        hi[j] = h;
        lo[j] = (half_t)((a[j] - (float)h) * 4096.f);
      }
      *(half8*)&Ah[r * SA + sko] = hi;
      *(half8*)&Al[r * SA + sko] = lo;
      const float* srcb = bp + (size_t)r * DIM + kd + sko;
      v0 = *(const float4*)srcb; v1 = *(const float4*)(srcb + 4);
      float b[8] = {v0.x, v0.y, v0.z, v0.w, v1.x, v1.y, v1.z, v1.w};
      #pragma unroll
      for (int j = 0; j < 8; ++j) {
        float bs = b[j] * 4096.f;
        half_t h = (half_t)bs;
        hi[j] = h;
        lo[j] = (half_t)((bs - (float)h) * 4096.f);
      }
      *(half8*)&Bh[r * SA + sko] = hi;
      *(half8*)&Bl[r * SA + sko] = lo;
    }
    __syncthreads();

    half8 fa_h[4], fa_l[4], fb_h[4], fb_l[4];
    #pragma unroll
    for (int t = 0; t < 4; ++t) {
      const int ar = (wm * 64 + t * 16 + l16) * SA + q * 8;
      fa_h[t] = *(const half8*)&Ah[ar];
      fa_l[t] = *(const half8*)&Al[ar];
      const int br = (wn * 64 + t * 16 + l16) * SA + q * 8;
      fb_h[t] = *(const half8*)&Bh[br];
      fb_l[t] = *(const half8*)&Bl[br];
    }
    #pragma unroll
    for (int tm = 0; tm < 4; ++tm)
      #pragma unroll
      for (int tn = 0; tn < 4; ++tn) {
        const int i = tm * 4 + tn;
        acc0[i] = __builtin_amdgcn_mfma_f32_16x16x32_f16(fa_h[tm], fb_h[tn], acc0[i], 0, 0, 0);
        acc1[i] = __builtin_amdgcn_mfma_f32_16x16x32_f16(fa_l[tm], fb_h[tn], acc1[i], 0, 0, 0);
        acc1[i] = __builtin_amdgcn_mfma_f32_16x16x32_f16(fa_h[tm], fb_l[tn], acc1[i], 0, 0, 0);
      }
  }

  const float c1 = 2.44140625e-4f;
  const float c2 = -4.8828125e-4f;
  #pragma unroll
  for (int tm = 0; tm < 4; ++tm) {
    #pragma unroll
    for (int reg = 0; reg < 4; ++reg) {
      const int row_b = wm * 64 + tm * 16 + q * 4 + reg;
      const float zs = lzs[row_b];
      float bd = FLT_MAX; int bi = 0x7fffffff;
      #pragma unroll
      for (int tn = 0; tn < 4; ++tn) {
        const int i = tm * 4 + tn;
        float v = fmaf(c1, acc1[i][reg], acc0[i][reg]);
        float d = fmaf(c2, v, zs);
        const int ci = code0 + wn * 64 + tn * 16 + l16;
        if (d < bd || (d == bd && ci < bi)) { bd = d; bi = ci; }
      }
      #pragma unroll
      for (int off = 8; off; off >>= 1) {
        float od = __shfl_xor(bd, off, 64);
        int   oi = __shfl_xor(bi, off, 64);
        if (od < bd || (od == bd && oi < bi)) { bd = od; bi = oi; }
      }
      if (l16 == 0) { redD[row_b][wn] = bd; redI[row_b][wn] = bi; }
    }
  }
  __syncthreads();
  if (tid < TM) {
    float d0 = redD[tid][0]; int i0 = redI[tid][0];
    float d1 = redD[tid][1]; int i1 = redI[tid][1];
    if (d1 < d0 || (d1 == d0 && i1 < i0)) { d0 = d1; i0 = i1; }
    unsigned long long key = ((unsigned long long)__float_as_uint(d0) << 32) | (unsigned int)i0;
    atomicMin(&keys[row0 + tid], key);
  }
}

__global__ void k2_codes(const unsigned long long* __restrict__ keys,
                         float* __restrict__ out_codes, int* __restrict__ codes_i) {
  const int r = blockIdx.x * 256 + threadIdx.x;
  const int idx = (int)(unsigned int)(keys[r] & 0xffffffffull);
  out_codes[r] = (float)idx;
  codes_i[r] = idx;
}

__global__ void k3_quant_loss(const float* __restrict__ z, const float* __restrict__ cb,
                              const int* __restrict__ codes, float* __restrict__ outq,
                              double* __restrict__ loss) {
  const int gid = blockIdx.x * blockDim.x + threadIdx.x;
  const int e0 = gid * 4;
  const int row = e0 / DIM;
  const int col = e0 - row * DIM;
  const int c = codes[row];
  const float4 zv = *(const float4*)(z + e0);
  const float4 qv = *(const float4*)(cb + (size_t)c * DIM + col);
  float d0 = qv.x - zv.x, d1 = qv.y - zv.y, d2 = qv.z - zv.z, d3 = qv.w - zv.w;
  float4 ov = { zv.x + d0, zv.y + d1, zv.z + d2, zv.w + d3 };
  *(float4*)(outq + e0) = ov;
  double s = (double)(d0 * d0) + (double)(d1 * d1) + (double)(d2 * d2) + (double)(d3 * d3);
  #pragma unroll
  for (int off = 32; off; off >>= 1) s += __shfl_xor(s, off, 64);
  __shared__ double wsum[4];
  const int wave = threadIdx.x >> 6, lane = threadIdx.x & 63;
  if (lane == 0) wsum[wave] = s;
  __syncthreads();
  if (threadIdx.x == 0) atomicAdd(loss, wsum[0] + wsum[1] + wsum[2] + wsum[3]);
}

extern "C" void kernel_launch(void* const* d_in, const int* in_sizes, int n_in,
                              void* d_out, int out_size, void* d_ws, size_t ws_size,
                              hipStream_t stream) {
  const float* z  = (const float*)d_in[0];
  const float* cb = (const float*)d_in[1];
  float* out = (float*)d_out;          // [codes 4096][q_ste 3145728][loss 1]
  char* ws = (char*)d_ws;
  float*  zsq = (float*)(ws + WS_ZSQ);
  unsigned int* runmin = (unsigned int*)(ws + WS_RUNMIN);
  int* cnt     = (int*)(ws + WS_CNT);
  int* codes_i = (int*)(ws + WS_CODESI);
  double* loss = (double*)(ws + WS_LOSS);
  int* list    = (int*)(ws + WS_LIST);
  unsigned long long* keys = (unsigned long long*)(ws + WS_LIST);

  if (ws_size >= WS_NEED) {
    half_t* Ahg = (half_t*)(ws + WS_AH);
    half_t* Bhg = (half_t*)(ws + WS_BH);
    dim3 g1s(NROWS / 256, KCODES / 256);
    k_convA<<<NROWS / 4, 256, 0, stream>>>(z, Ahg, zsq, runmin, cnt, loss);
    k_convB<<<(KCODES * DIM / 8 + 255) / 256, 256, 0, stream>>>(cb, Bhg, KCODES * DIM / 8);
    k1_s1<<<g1s, 512, 0, stream>>>(Ahg, Bhg, zsq, runmin, cnt, list);
    k_refine<<<NROWS, 256, 0, stream>>>(z, cb, zsq, cnt, list, out, out + NROWS, loss);
  } else {
    dim3 g1(NROWS / TM, KCODES / TC);
    k0_zsq<<<NROWS / 4, 256, 0, stream>>>(z, zsq, keys, loss);
    k1_mfma<<<g1, 256, 0, stream>>>(z, cb, zsq, keys);
    k2_codes<<<NROWS / 256, 256, 0, stream>>>(keys, out, codes_i);
    k3_quant_loss<<<(NROWS * DIM / 4) / 256, 256, 0, stream>>>(z, cb, codes_i, out + NROWS, loss);
  }

  k4_final<<<1, 1, 0, stream>>>(loss, out + NROWS + (size_t)NROWS * DIM);
}

// Round 3
// 950.749 us; speedup vs baseline: 1.1241x; 1.0520x over previous
//
#include <hip/hip_runtime.h>
#include <cfloat>
#include <cstdint>

#define NROWS  4096
#define DIM    768
#define KCODES 65536

#define TM 128
#define TC 128
#define BK 64          // K-chunk (halves); 128-B LDS row stride (r3-verified swizzle geometry)
#define SA 40          // fallback path LDS stride
#define CAP 2048       // candidate list slots per row
#define DELTA 3.0e-4f  // guaranteed screening margin (worst-case err chain ~1.6e-4)

// workspace layout (bytes)
#define WS_ZSQ    0                          // 4096 f32
#define WS_RUNMIN 16384                      // 4096 u32
#define WS_CNT    32768                      // 4096 i32
#define WS_CODESI 49152                      // 4096 i32 (fallback)
#define WS_LOSS   65536                      // 1 f64
#define WS_LIST   131072                     // 4096*CAP i32 = 32 MB (fallback: keys u64)
#define WS_AH     (WS_LIST + (size_t)NROWS*CAP*4)
#define WS_BH     (WS_AH + (size_t)NROWS*DIM*2)
#define WS_NEED   (WS_BH + (size_t)KCODES*DIM*2)

typedef _Float16 half_t;
typedef _Float16 half4 __attribute__((ext_vector_type(4)));
typedef _Float16 half8 __attribute__((ext_vector_type(8)));
typedef float    f32x4 __attribute__((ext_vector_type(4)));
typedef unsigned int uint;
typedef __attribute__((address_space(3))) half_t lds_half_t;

__device__ __forceinline__ void gld16(half_t* lds, const half_t* g) {
  __builtin_amdgcn_global_load_lds(
      (const __attribute__((address_space(1))) unsigned int*)g,
      (__attribute__((address_space(3))) unsigned int*)lds, 16, 0, 0);
}

// ---- k_convA: z -> fp16 hi, z_sq per row, init runmin/cnt, zero loss ------
__global__ void k_convA(const float* __restrict__ z, half_t* __restrict__ h,
                        float* __restrict__ zsq, unsigned int* __restrict__ runmin,
                        int* __restrict__ cnt, double* __restrict__ loss) {
  const int wave = threadIdx.x >> 6, lane = threadIdx.x & 63;
  const int row = blockIdx.x * 4 + wave;
  const float4* zr = (const float4*)(z + (size_t)row * DIM);
  half_t* hr = h + (size_t)row * DIM;
  float s = 0.f;
  #pragma unroll
  for (int p = 0; p < 3; ++p) {
    float4 v = zr[lane + p * 64];
    s = fmaf(v.x, v.x, s); s = fmaf(v.y, v.y, s);
    s = fmaf(v.z, v.z, s); s = fmaf(v.w, v.w, s);
    half4 hv = { (half_t)v.x, (half_t)v.y, (half_t)v.z, (half_t)v.w };
    *(half4*)(hr + (lane + p * 64) * 4) = hv;
  }
  #pragma unroll
  for (int off = 32; off; off >>= 1) s += __shfl_xor(s, off, 64);
  if (lane == 0) zsq[row] = s;
  const int gid = blockIdx.x * 256 + threadIdx.x;
  if (gid < NROWS) { runmin[gid] = 0x7f7fffffu; cnt[gid] = 0; }
  if (gid == 0) *loss = 0.0;
}

// ---- k_convB: cb -> fp16 hi, prescaled by 4096 ----------------------------
__global__ void k_convB(const float* __restrict__ src, half_t* __restrict__ h, int n8) {
  const int i = blockIdx.x * 256 + threadIdx.x;
  if (i >= n8) return;
  float4 v0 = ((const float4*)src)[2 * i];
  float4 v1 = ((const float4*)src)[2 * i + 1];
  float a[8] = {v0.x, v0.y, v0.z, v0.w, v1.x, v1.y, v1.z, v1.w};
  half8 hi;
  #pragma unroll
  for (int j = 0; j < 8; ++j) hi[j] = (half_t)(a[j] * 4096.f);
  ((half8*)h)[i] = hi;
}

// ---- k1_s1: 256x256-tile 8-phase fp16 MFMA screen + candidate collection --
// v3: same verified staging/gate/barrier schedule as v1/v2; ds_reads reduced
// to read-once (96 -> 60 b128 per iter) via register-held fa[8]/fb[4] banks,
// and issued one phase EARLY (post-MFMA of the previous phase) so LDS latency
// and pipe time hide under gate/barrier/stage instead of serializing with MFMA.
// Newly-gated regions (buf.A0/B0 right after GATE4) are read at the START of
// the following phase (= after the gate's trailing barrier) because a wave's
// own vmcnt gate does not retire other waves' staging loads.
//
// Steady-state per iter t (buf0 = tile 2t phases p1-4, buf1 = 2t+1 p5-8):
//   stage:  p1 buf1.A1@kdB  p2 buf1.B0@kdB  p3 buf0.A0@kdN0  p4 buf0.B1@kdN0
//           p5 buf0.A1@kdN0 p6 buf0.B0@kdN0 p7 buf1.A0@kdN1  p8 buf1.B1@kdN1
//   gates:  vmcnt(4) end of p4 and p8 (unchanged)
//   reads:  p1 start fa<-A0(b0),fb<-B0(b0); p1 post fb<-B1(b0)
//           p2 post fa<-A1(b0); p3 post fb<-B0(b0); p4 post none
//           p5 start fa<-A0(b1),fb<-B0(b1); p5 post fb<-B1(b1)
//           p6 post fa<-A1(b1); p7 post fb<-B0(b1); p8 post none

#define GATE4 asm volatile("s_waitcnt vmcnt(4)" ::: "memory")
#define GATE0 asm volatile("s_waitcnt vmcnt(0)" ::: "memory")
#define GATEN
#define NOSTAGE
#define NORD

#define DSR(dst, base, imm) \
  asm volatile("ds_read_b128 %0, %1 offset:%2" : "=v"(dst) : "v"(base), "n"(imm))

#define RD_FA(BUF, H) { \
  DSR(fa0, rA00, (BUF)*32768 + (H)*16384 + 0); \
  DSR(fa1, rA01, (BUF)*32768 + (H)*16384 + 0); \
  DSR(fa2, rA00, (BUF)*32768 + (H)*16384 + 2048); \
  DSR(fa3, rA01, (BUF)*32768 + (H)*16384 + 2048); \
  DSR(fa4, rA00, (BUF)*32768 + (H)*16384 + 4096); \
  DSR(fa5, rA01, (BUF)*32768 + (H)*16384 + 4096); \
  DSR(fa6, rA00, (BUF)*32768 + (H)*16384 + 6144); \
  DSR(fa7, rA01, (BUF)*32768 + (H)*16384 + 6144); }

#define RD_FB(BUF, G) { \
  DSR(fb0, rB00, (BUF)*32768 + (G)*16384 + 0); \
  DSR(fb1, rB01, (BUF)*32768 + (G)*16384 + 0); \
  DSR(fb2, rB00, (BUF)*32768 + (G)*16384 + 2048); \
  DSR(fb3, rB01, (BUF)*32768 + (G)*16384 + 2048); }

#define MFMA2(AI, Ax0, Ax1, Bx0, Bx1) \
  acc[AI] = __builtin_amdgcn_mfma_f32_16x16x32_f16(Ax0, Bx0, acc[AI], 0, 0, 0); \
  acc[AI] = __builtin_amdgcn_mfma_f32_16x16x32_f16(Ax1, Bx1, acc[AI], 0, 0, 0)

#define STAGE_A(BUF, H, KD) { \
  gld16(stA + (BUF)*16384 + ((H)*128 +  0)*64, gAbase + (size_t)(((H)*64 +   0)*DIM) + (KD)); \
  gld16(stA + (BUF)*16384 + ((H)*128 + 64)*64, gAbase + (size_t)(((H)*64 + 128)*DIM) + (KD)); }

#define STAGE_B(BUF, G, KD) { \
  gld16(stB + (BUF)*16384 + ((G)*128 +  0)*64, gBbase + (size_t)(((G)*32 +   0)*DIM) + (KD)); \
  gld16(stB + (BUF)*16384 + ((G)*128 + 64)*64, gBbase + (size_t)(((G)*32 + 128)*DIM) + (KD)); }

#define PHASE(H, G, STARTRD, STAGE, GATE, POSTRD) { \
  STARTRD; \
  STAGE; \
  __builtin_amdgcn_s_barrier(); \
  asm volatile("s_waitcnt lgkmcnt(0)" ::: "memory"); \
  __builtin_amdgcn_sched_barrier(0); \
  __builtin_amdgcn_s_setprio(1); \
  MFMA2(((H)*4+0)*4 + (G)*2 + 0, fa0, fa1, fb0, fb1); \
  MFMA2(((H)*4+0)*4 + (G)*2 + 1, fa0, fa1, fb2, fb3); \
  MFMA2(((H)*4+1)*4 + (G)*2 + 0, fa2, fa3, fb0, fb1); \
  MFMA2(((H)*4+1)*4 + (G)*2 + 1, fa2, fa3, fb2, fb3); \
  MFMA2(((H)*4+2)*4 + (G)*2 + 0, fa4, fa5, fb0, fb1); \
  MFMA2(((H)*4+2)*4 + (G)*2 + 1, fa4, fa5, fb2, fb3); \
  MFMA2(((H)*4+3)*4 + (G)*2 + 0, fa6, fa7, fb0, fb1); \
  MFMA2(((H)*4+3)*4 + (G)*2 + 1, fa6, fa7, fb2, fb3); \
  __builtin_amdgcn_s_setprio(0); \
  __builtin_amdgcn_sched_barrier(0); \
  GATE; \
  POSTRD; \
  __builtin_amdgcn_s_barrier(); }

__global__ __launch_bounds__(512, 2) void k1_s1(
    const half_t* __restrict__ Ahg, const half_t* __restrict__ Bhg,
    const float* __restrict__ zsq, unsigned int* __restrict__ runmin,
    int* __restrict__ cnt, int* __restrict__ list) {
  __shared__ __align__(16) half_t sA[2][256 * 64];   // 64 KB
  __shared__ __align__(16) half_t sB[2][256 * 64];   // 64 KB
  __shared__ float lzs[256];
  __shared__ float redD[256][4];
  __shared__ float lbound[256];

  const int tid = threadIdx.x;
  const int row0  = blockIdx.x * 256;
  const int code0 = blockIdx.y * 256;
  const int wave = tid >> 6, lane = tid & 63;
  const int wm = wave >> 2, wn = wave & 3;
  const int q = lane >> 4, l16 = lane & 15;
  const int sr = lane >> 3, ss = lane & 7;
  const int gsw8 = (ss ^ sr) * 8;
  const int s0 = wave * 8 + sr;                    // staging sub-row 0..63

  if (tid < 256) lzs[tid] = zsq[row0 + tid];

  // ---- hoisted LDS read bases (bytes, as3 addresses) ----
  const uint ldsA = (uint)(size_t)(lds_half_t*)&sA[0][0];
  const uint ldsB = (uint)(size_t)(lds_half_t*)&sB[0][0];
  const int xr = l16 & 7;
  const uint rA00 = ldsA + (uint)((wm * 64 + l16) * 128 + ((q ^ xr) * 16));
  const uint rA01 = ldsA + (uint)((wm * 64 + l16) * 128 + (((4 + q) ^ xr) * 16));
  const uint rB00 = ldsB + (uint)((wn * 32 + l16) * 128 + ((q ^ xr) * 16));
  const uint rB01 = ldsB + (uint)((wn * 32 + l16) * 128 + (((4 + q) ^ xr) * 16));

  // ---- hoisted staging bases ----
  half_t* stA = &sA[0][0] + s0 * 64 + ss * 8;
  half_t* stB = &sB[0][0] + s0 * 64 + ss * 8;
  const half_t* gAbase = Ahg + (size_t)(row0 + s0) * DIM + gsw8;
  const half_t* gBbase = Bhg + (size_t)(code0 + (s0 >> 5) * 64 + (s0 & 31)) * DIM + gsw8;

  // fragment register banks (read-once, held across phases)
  half8 fa0, fa1, fa2, fa3, fa4, fa5, fa6, fa7;
  half8 fb0, fb1, fb2, fb3;

  f32x4 acc[32];
  #pragma unroll
  for (int i = 0; i < 32; ++i) acc[i] = (f32x4){0.f, 0.f, 0.f, 0.f};

  // prologue: buf0 <- tile0 (A0,B1,A1,B0), buf1 early units <- tile1 (A0,B1)
  STAGE_A(0, 0, 0);  STAGE_B(0, 1, 0);  STAGE_A(0, 1, 0);  STAGE_B(0, 0, 0);
  STAGE_A(1, 0, 64); STAGE_B(1, 1, 64);
  GATE4;                                        // buf0 fully landed (allow 2 buf1 units)
  asm volatile("s_waitcnt lgkmcnt(0)" ::: "memory");  // lzs ds_write visible
  __builtin_amdgcn_s_barrier();

  for (int t = 0; t < 5; ++t) {
    const int kdB  = t * 128 + 64;   // buf1 current tile (late units A1,B0)
    const int kdN0 = t * 128 + 128;  // buf0 next tile
    const int kdN1 = t * 128 + 192;  // buf1 next tile (early units A0,B1)
    PHASE(0, 0, { RD_FA(0,0); RD_FB(0,0); }, STAGE_A(1, 1, kdB),  GATEN, RD_FB(0,1));
    PHASE(0, 1, NORD,                        STAGE_B(1, 0, kdB),  GATEN, RD_FA(0,1));
    PHASE(1, 1, NORD,                        STAGE_A(0, 0, kdN0), GATEN, RD_FB(0,0));
    PHASE(1, 0, NORD,                        STAGE_B(0, 1, kdN0), GATE4, NORD);
    PHASE(0, 0, { RD_FA(1,0); RD_FB(1,0); }, STAGE_A(0, 1, kdN0), GATEN, RD_FB(1,1));
    PHASE(0, 1, NORD,                        STAGE_B(0, 0, kdN0), GATEN, RD_FA(1,1));
    PHASE(1, 1, NORD,                        STAGE_A(1, 0, kdN1), GATEN, RD_FB(1,0));
    PHASE(1, 0, NORD,                        STAGE_B(1, 1, kdN1), GATE4, NORD);
  }
  { // tail iter t=5: only tile-11 late units remain to stage
    PHASE(0, 0, { RD_FA(0,0); RD_FB(0,0); }, STAGE_A(1, 1, 704), GATEN, RD_FB(0,1));
    PHASE(0, 1, NORD,                        STAGE_B(1, 0, 704), GATEN, RD_FA(0,1));
    PHASE(1, 1, NORD,                        NOSTAGE,            GATEN, RD_FB(0,0));
    PHASE(1, 0, NORD,                        NOSTAGE,            GATE0, NORD);
    PHASE(0, 0, { RD_FA(1,0); RD_FB(1,0); }, NOSTAGE,            GATEN, RD_FB(1,1));
    PHASE(0, 1, NORD,                        NOSTAGE,            GATEN, RD_FA(1,1));
    PHASE(1, 1, NORD,                        NOSTAGE,            GATEN, RD_FB(1,0));
    PHASE(1, 0, NORD,                        NOSTAGE,            GATEN, NORD);
  }

  // transform acc -> approx distance d~ = fl(zs - 2^-11 * acc)
  const float c2 = -4.8828125e-4f;   // -2^-11 (B prescaled by 4096)
  #pragma unroll
  for (int tm = 0; tm < 8; ++tm)
    #pragma unroll
    for (int reg = 0; reg < 4; ++reg) {
      const float zs = lzs[wm * 128 + tm * 16 + q * 4 + reg];
      #pragma unroll
      for (int tn = 0; tn < 4; ++tn)
        acc[tm * 4 + tn][reg] = fmaf(c2, acc[tm * 4 + tn][reg], zs);
    }

  // block-local per-row min
  #pragma unroll
  for (int tm = 0; tm < 8; ++tm)
    #pragma unroll
    for (int reg = 0; reg < 4; ++reg) {
      float m = acc[tm * 4 + 0][reg];
      #pragma unroll
      for (int tn = 1; tn < 4; ++tn) m = fminf(m, acc[tm * 4 + tn][reg]);
      #pragma unroll
      for (int off = 8; off; off >>= 1) m = fminf(m, __shfl_xor(m, off, 64));
      if (l16 == 0) redD[wm * 128 + tm * 16 + q * 4 + reg][wn] = m;
    }
  __syncthreads();
  if (tid < 256) {
    const float lm = fminf(fminf(redD[tid][0], redD[tid][1]),
                           fminf(redD[tid][2], redD[tid][3]));
    const unsigned rg = runmin[row0 + tid];          // stale-safe: always >= true min
    atomicMin(&runmin[row0 + tid], __float_as_uint(lm));
    lbound[tid] = fminf(lm, __uint_as_float(rg)) + DELTA;
  }
  __syncthreads();

  // collect candidates within margin (provably includes reference winner + ties)
  #pragma unroll
  for (int tm = 0; tm < 8; ++tm)
    #pragma unroll
    for (int reg = 0; reg < 4; ++reg) {
      const int row_b = wm * 128 + tm * 16 + q * 4 + reg;
      const float b = lbound[row_b];
      #pragma unroll
      for (int tn = 0; tn < 4; ++tn) {
        const float d = acc[tm * 4 + tn][reg];
        if (d <= b) {
          const int grow = row0 + row_b;
          const int pos = atomicAdd(&cnt[grow], 1);
          if (pos < CAP) list[(size_t)grow * CAP + pos] = code0 + wn * 64 + tn * 16 + l16;
        }
      }
    }
}

// ---- k_refine: fp64 re-score of survivors + gather + STE + loss (fused) ---
__global__ void k_refine(const float* __restrict__ z, const float* __restrict__ cb,
                         const float* __restrict__ zsq, const int* __restrict__ cnt,
                         const int* __restrict__ list, float* __restrict__ out_codes,
                         float* __restrict__ outq, double* __restrict__ loss) {
  const int r = blockIdx.x;
  const int tid = threadIdx.x, wave = tid >> 6, lane = tid & 63;
  __shared__ unsigned long long wbest[4];
  __shared__ double wsum[4];
  __shared__ int sidx;
  __shared__ __align__(16) float zsh[DIM];

  if (tid < DIM / 4) ((float4*)zsh)[tid] = ((const float4*)(z + (size_t)r * DIM))[tid];
  __syncthreads();

  int n = cnt[r]; if (n > CAP) n = CAP;
  const bool empty = (n == 0); if (empty) n = 1;   // winner provably collected; guard anyway
  const double zsd = (double)zsq[r];
  unsigned long long best = ~0ull;
  for (int ci = wave; ci < n; ci += 4) {
    const int idx = empty ? 0 : list[(size_t)r * CAP + ci];
    const float4* cr = (const float4*)(cb + (size_t)idx * DIM);
    double s = 0.0;
    #pragma unroll
    for (int p = 0; p < 3; ++p) {
      const float4 cv = cr[lane + p * 64];
      const float4 zv = ((const float4*)zsh)[lane + p * 64];
      s += (double)zv.x * cv.x + (double)zv.y * cv.y +
           (double)zv.z * cv.z + (double)zv.w * cv.w;
    }
    #pragma unroll
    for (int off = 32; off; off >>= 1) s += __shfl_xor(s, off, 64);
    const float d = (float)(zsd - 2.0 * s);        // single rounding, ref semantics
    const unsigned long long key =
        ((unsigned long long)__float_as_uint(d) << 32) | (unsigned)idx;
    if (key < best) best = key;                    // (d, idx) lexicographic
  }
  if (lane == 0) wbest[wave] = best;
  __syncthreads();
  if (tid == 0) {
    unsigned long long b = wbest[0];
    #pragma unroll
    for (int w = 1; w < 4; ++w) if (wbest[w] < b) b = wbest[w];
    const int idx = (int)(unsigned)(b & 0xffffffffull);
    sidx = idx;
    out_codes[r] = (float)idx;
  }
  __syncthreads();

  const int c = sidx;
  double ls = 0.0;
  #pragma unroll
  for (int j = 0; j < 3; ++j) {
    const int e = tid + j * 256;
    const float qx = cb[(size_t)c * DIM + e];
    const float zx = zsh[e];
    const float dd = qx - zx;
    outq[(size_t)r * DIM + e] = zx + dd;           // fl(z + fl(q-z)) bitwise
    ls += (double)dd * (double)dd;
  }
  #pragma unroll
  for (int off = 32; off; off >>= 1) ls += __shfl_xor(ls, off, 64);
  if (lane == 0) wsum[wave] = ls;
  __syncthreads();
  if (tid == 0) atomicAdd(loss, wsum[0] + wsum[1] + wsum[2] + wsum[3]);
}

// ---- k4: finalize loss -----------------------------------------------------
__global__ void k4_final(const double* __restrict__ loss, float* __restrict__ out) {
  float m = (float)(*loss / ((double)NROWS * (double)DIM));
  out[0] = m + 0.25f * m;
}

// ======================= fallback path (ws too small) =======================
__global__ void k0_zsq(const float* __restrict__ z, float* __restrict__ zsq,
                       unsigned long long* __restrict__ keys, double* __restrict__ loss) {
  const int wave = threadIdx.x >> 6, lane = threadIdx.x & 63;
  const int row = blockIdx.x * 4 + wave;
  const float* zr = z + (size_t)row * DIM;
  float s = 0.f;
  #pragma unroll
  for (int i = 0; i < DIM / 64; ++i) { float v = zr[lane + i * 64]; s = fmaf(v, v, s); }
  #pragma unroll
  for (int off = 32; off; off >>= 1) s += __shfl_xor(s, off, 64);
  if (lane == 0) zsq[row] = s;
  const int gid = blockIdx.x * 256 + threadIdx.x;
  if (gid < NROWS) keys[gid] = ~0ull;
  if (gid == 0) *loss = 0.0;
}

__global__ __launch_bounds__(256, 2) void k1_mfma(
    const float* __restrict__ z, const float* __restrict__ cb,
    const float* __restrict__ zsq, unsigned long long* __restrict__ keys) {
  __shared__ half_t Ah[TM * SA], Al[TM * SA], Bh[TC * SA], Bl[TC * SA];
  __shared__ float lzs[TM];
  __shared__ float redD[TM][2];
  __shared__ int   redI[TM][2];

  const int tid  = threadIdx.x;
  const int row0  = blockIdx.x * TM;
  const int code0 = blockIdx.y * TC;
  const int wave = tid >> 6, lane = tid & 63;
  const int wm = wave & 1, wn = wave >> 1;
  const int q = lane >> 4, l16 = lane & 15;

  if (tid < TM) lzs[tid] = zsq[row0 + tid];

  const int srow = tid >> 2;
  const int sko  = (tid & 3) * 8;

  f32x4 acc0[16], acc1[16];
  #pragma unroll
  for (int i = 0; i < 16; ++i) {
    acc0[i] = (f32x4){0.f, 0.f, 0.f, 0.f};
    acc1[i] = (f32x4){0.f, 0.f, 0.f, 0.f};
  }

  const float* zp = z  + (size_t)row0  * DIM;
  const float* bp = cb + (size_t)code0 * DIM;

  for (int kd = 0; kd < DIM; kd += 32) {
    __syncthreads();
    #pragma unroll
    for (int s = 0; s < 2; ++s) {
      const int r = srow + s * 64;
      const float* srca = zp + (size_t)r * DIM + kd + sko;
      float4 v0 = *(const float4*)srca;
      float4 v1 = *(const float4*)(srca + 4);
      float a[8] = {v0.x, v0.y, v0.z, v0.w, v1.x, v1.y, v1.z, v1.w};
      half8 hi, lo;
      #pragma unroll
      for (int j = 0; j < 8; ++j) {
        half_t h = (half_t)a[j];
        hi[j] = h;
        lo[j] = (half_t)((a[j] - (float)h) * 4096.f);
      }
      *(half8*)&Ah[r * SA + sko] = hi;
      *(half8*)&Al[r * SA + sko] = lo;
      const float* srcb = bp + (size_t)r * DIM + kd + sko;
      v0 = *(const float4*)srcb; v1 = *(const float4*)(srcb + 4);
      float b[8] = {v0.x, v0.y, v0.z, v0.w, v1.x, v1.y, v1.z, v1.w};
      #pragma unroll
      for (int j = 0; j < 8; ++j) {
        float bs = b[j] * 4096.f;
        half_t h = (half_t)bs;
        hi[j] = h;
        lo[j] = (half_t)((bs - (float)h) * 4096.f);
      }
      *(half8*)&Bh[r * SA + sko] = hi;
      *(half8*)&Bl[r * SA + sko] = lo;
    }
    __syncthreads();

    half8 fa_h[4], fa_l[4], fb_h[4], fb_l[4];
    #pragma unroll
    for (int t = 0; t < 4; ++t) {
      const int ar = (wm * 64 + t * 16 + l16) * SA + q * 8;
      fa_h[t] = *(const half8*)&Ah[ar];
      fa_l[t] = *(const half8*)&Al[ar];
      const int br = (wn * 64 + t * 16 + l16) * SA + q * 8;
      fb_h[t] = *(const half8*)&Bh[br];
      fb_l[t] = *(const half8*)&Bl[br];
    }
    #pragma unroll
    for (int tm = 0; tm < 4; ++tm)
      #pragma unroll
      for (int tn = 0; tn < 4; ++tn) {
        const int i = tm * 4 + tn;
        acc0[i] = __builtin_amdgcn_mfma_f32_16x16x32_f16(fa_h[tm], fb_h[tn], acc0[i], 0, 0, 0);
        acc1[i] = __builtin_amdgcn_mfma_f32_16x16x32_f16(fa_l[tm], fb_h[tn], acc1[i], 0, 0, 0);
        acc1[i] = __builtin_amdgcn_mfma_f32_16x16x32_f16(fa_h[tm], fb_l[tn], acc1[i], 0, 0, 0);
      }
  }

  const float c1 = 2.44140625e-4f;
  const float c2 = -4.8828125e-4f;
  #pragma unroll
  for (int tm = 0; tm < 4; ++tm) {
    #pragma unroll
    for (int reg = 0; reg < 4; ++reg) {
      const int row_b = wm * 64 + tm * 16 + q * 4 + reg;
      const float zs = lzs[row_b];
      float bd = FLT_MAX; int bi = 0x7fffffff;
      #pragma unroll
      for (int tn = 0; tn < 4; ++tn) {
        const int i = tm * 4 + tn;
        float v = fmaf(c1, acc1[i][reg], acc0[i][reg]);
        float d = fmaf(c2, v, zs);
        const int ci = code0 + wn * 64 + tn * 16 + l16;
        if (d < bd || (d == bd && ci < bi)) { bd = d; bi = ci; }
      }
      #pragma unroll
      for (int off = 8; off; off >>= 1) {
        float od = __shfl_xor(bd, off, 64);
        int   oi = __shfl_xor(bi, off, 64);
        if (od < bd || (od == bd && oi < bi)) { bd = od; bi = oi; }
      }
      if (l16 == 0) { redD[row_b][wn] = bd; redI[row_b][wn] = bi; }
    }
  }
  __syncthreads();
  if (tid < TM) {
    float d0 = redD[tid][0]; int i0 = redI[tid][0];
    float d1 = redD[tid][1]; int i1 = redI[tid][1];
    if (d1 < d0 || (d1 == d0 && i1 < i0)) { d0 = d1; i0 = i1; }
    unsigned long long key = ((unsigned long long)__float_as_uint(d0) << 32) | (unsigned int)i0;
    atomicMin(&keys[row0 + tid], key);
  }
}

__global__ void k2_codes(const unsigned long long* __restrict__ keys,
                         float* __restrict__ out_codes, int* __restrict__ codes_i) {
  const int r = blockIdx.x * 256 + threadIdx.x;
  const int idx = (int)(unsigned int)(keys[r] & 0xffffffffull);
  out_codes[r] = (float)idx;
  codes_i[r] = idx;
}

__global__ void k3_quant_loss(const float* __restrict__ z, const float* __restrict__ cb,
                              const int* __restrict__ codes, float* __restrict__ outq,
                              double* __restrict__ loss) {
  const int gid = blockIdx.x * blockDim.x + threadIdx.x;
  const int e0 = gid * 4;
  const int row = e0 / DIM;
  const int col = e0 - row * DIM;
  const int c = codes[row];
  const float4 zv = *(const float4*)(z + e0);
  const float4 qv = *(const float4*)(cb + (size_t)c * DIM + col);
  float d0 = qv.x - zv.x, d1 = qv.y - zv.y, d2 = qv.z - zv.z, d3 = qv.w - zv.w;
  float4 ov = { zv.x + d0, zv.y + d1, zv.z + d2, zv.w + d3 };
  *(float4*)(outq + e0) = ov;
  double s = (double)(d0 * d0) + (double)(d1 * d1) + (double)(d2 * d2) + (double)(d3 * d3);
  #pragma unroll
  for (int off = 32; off; off >>= 1) s += __shfl_xor(s, off, 64);
  __shared__ double wsum[4];
  const int wave = threadIdx.x >> 6, lane = threadIdx.x & 63;
  if (lane == 0) wsum[wave] = s;
  __syncthreads();
  if (threadIdx.x == 0) atomicAdd(loss, wsum[0] + wsum[1] + wsum[2] + wsum[3]);
}

extern "C" void kernel_launch(void* const* d_in, const int* in_sizes, int n_in,
                              void* d_out, int out_size, void* d_ws, size_t ws_size,
                              hipStream_t stream) {
  const float* z  = (const float*)d_in[0];
  const float* cb = (const float*)d_in[1];
  float* out = (float*)d_out;          // [codes 4096][q_ste 3145728][loss 1]
  char* ws = (char*)d_ws;
  float*  zsq = (float*)(ws + WS_ZSQ);
  unsigned int* runmin = (unsigned int*)(ws + WS_RUNMIN);
  int* cnt     = (int*)(ws + WS_CNT);
  int* codes_i = (int*)(ws + WS_CODESI);
  double* loss = (double*)(ws + WS_LOSS);
  int* list    = (int*)(ws + WS_LIST);
  unsigned long long* keys = (unsigned long long*)(ws + WS_LIST);

  if (ws_size >= WS_NEED) {
    half_t* Ahg = (half_t*)(ws + WS_AH);
    half_t* Bhg = (half_t*)(ws + WS_BH);
    dim3 g1s(NROWS / 256, KCODES / 256);
    k_convA<<<NROWS / 4, 256, 0, stream>>>(z, Ahg, zsq, runmin, cnt, loss);
    k_convB<<<(KCODES * DIM / 8 + 255) / 256, 256, 0, stream>>>(cb, Bhg, KCODES * DIM / 8);
    k1_s1<<<g1s, 512, 0, stream>>>(Ahg, Bhg, zsq, runmin, cnt, list);
    k_refine<<<NROWS, 256, 0, stream>>>(z, cb, zsq, cnt, list, out, out + NROWS, loss);
  } else {
    dim3 g1(NROWS / TM, KCODES / TC);
    k0_zsq<<<NROWS / 4, 256, 0, stream>>>(z, zsq, keys, loss);
    k1_mfma<<<g1, 256, 0, stream>>>(z, cb, zsq, keys);
    k2_codes<<<NROWS / 256, 256, 0, stream>>>(keys, out, codes_i);
    k3_quant_loss<<<(NROWS * DIM / 4) / 256, 256, 0, stream>>>(z, cb, codes_i, out + NROWS, loss);
  }

  k4_final<<<1, 1, 0, stream>>>(loss, out + NROWS + (size_t)NROWS * DIM);
}

// Round 4
// 945.082 us; speedup vs baseline: 1.1308x; 1.0060x over previous
//
#include <hip/hip_runtime.h>
#include <cfloat>
#include <cstdint>

#define NROWS  4096
#define DIM    768
#define KCODES 65536

#define TM 128
#define TC 128
#define BK 64          // K-chunk (halves); 128-B LDS row stride (r3-verified swizzle geometry)
#define SA 40          // fallback path LDS stride
#define CAP 2048       // candidate list slots per row
#define DELTA 3.0e-4f  // guaranteed screening margin (worst-case err chain ~1.6e-4)

// workspace layout (bytes)
#define WS_ZSQ    0                          // 4096 f32
#define WS_RUNMIN 16384                      // 4096 u32
#define WS_CNT    32768                      // 4096 i32
#define WS_CODESI 49152                      // 4096 i32 (fallback)
#define WS_LOSS   65536                      // 1 f64
#define WS_LIST   131072                     // 4096*CAP i32 = 32 MB (fallback: keys u64)
#define WS_AH     (WS_LIST + (size_t)NROWS*CAP*4)
#define WS_BH     (WS_AH + (size_t)NROWS*DIM*2)
#define WS_NEED   (WS_BH + (size_t)KCODES*DIM*2)

typedef _Float16 half_t;
typedef _Float16 half4 __attribute__((ext_vector_type(4)));
typedef _Float16 half8 __attribute__((ext_vector_type(8)));
typedef float    f32x4 __attribute__((ext_vector_type(4)));
typedef unsigned int uint;
typedef __attribute__((address_space(3))) half_t lds_half_t;

__device__ __forceinline__ void gld16(half_t* lds, const half_t* g) {
  __builtin_amdgcn_global_load_lds(
      (const __attribute__((address_space(1))) unsigned int*)g,
      (__attribute__((address_space(3))) unsigned int*)lds, 16, 0, 0);
}

// ---- k_convA: z -> fp16 hi, z_sq per row, init runmin/cnt, zero loss ------
__global__ void k_convA(const float* __restrict__ z, half_t* __restrict__ h,
                        float* __restrict__ zsq, unsigned int* __restrict__ runmin,
                        int* __restrict__ cnt, double* __restrict__ loss) {
  const int wave = threadIdx.x >> 6, lane = threadIdx.x & 63;
  const int row = blockIdx.x * 4 + wave;
  const float4* zr = (const float4*)(z + (size_t)row * DIM);
  half_t* hr = h + (size_t)row * DIM;
  float s = 0.f;
  #pragma unroll
  for (int p = 0; p < 3; ++p) {
    float4 v = zr[lane + p * 64];
    s = fmaf(v.x, v.x, s); s = fmaf(v.y, v.y, s);
    s = fmaf(v.z, v.z, s); s = fmaf(v.w, v.w, s);
    half4 hv = { (half_t)v.x, (half_t)v.y, (half_t)v.z, (half_t)v.w };
    *(half4*)(hr + (lane + p * 64) * 4) = hv;
  }
  #pragma unroll
  for (int off = 32; off; off >>= 1) s += __shfl_xor(s, off, 64);
  if (lane == 0) zsq[row] = s;
  const int gid = blockIdx.x * 256 + threadIdx.x;
  if (gid < NROWS) { runmin[gid] = 0x7f7fffffu; cnt[gid] = 0; }
  if (gid == 0) *loss = 0.0;
}

// ---- k_convB: cb -> fp16 hi, prescaled by 4096 ----------------------------
__global__ void k_convB(const float* __restrict__ src, half_t* __restrict__ h, int n8) {
  const int i = blockIdx.x * 256 + threadIdx.x;
  if (i >= n8) return;
  float4 v0 = ((const float4*)src)[2 * i];
  float4 v1 = ((const float4*)src)[2 * i + 1];
  float a[8] = {v0.x, v0.y, v0.z, v0.w, v1.x, v1.y, v1.z, v1.w};
  half8 hi;
  #pragma unroll
  for (int j = 0; j < 8; ++j) hi[j] = (half_t)(a[j] * 4096.f);
  ((half8*)h)[i] = hi;
}

// ---- k1_s1: 256x256-tile 8-phase fp16 MFMA screen + candidate collection --
// v4: identical staging/gate/barrier schedule + dataflow as v3 (absmax=0 twice);
// phase body restructured:
//   - 16 MFMA split into 2 clusters of 8 INDEPENDENT ops (k-slice 0 then 1)
//     -> no acc-dependency stalls at 2 waves/SIMD
//   - B fragments double-banked (fbA/fbB); the 4 B-reads of the next sub-tile
//     issue BETWEEN the clusters (clobber-free by bank parity) -> LDS pipe
//     overlaps matrix pipe. A reads stay at v3 post slot (single bank).
//   - p4 reuses fbA from p1-start, p8 reuses fbB from p5-start: redundant B
//     re-reads dropped (48 ds_read_b128/iter = read-once minimum).
//
// Steady-state per iter t (buf0 = tile 2t p1-4, buf1 = 2t+1 p5-8):
//   stage:  p1 b1.A1@kdB  p2 b1.B0@kdB  p3 b0.A0@kdN0  p4 b0.B1@kdN0
//           p5 b0.A1@kdN0 p6 b0.B0@kdN0 p7 b1.A0@kdN1  p8 b1.B1@kdN1
//   gates:  vmcnt(4) end of p4/p8 (unchanged; tail p4 = vmcnt(0))
//   reads:  p1 start fa<-A0(b0), fbA<-B0(b0);  p1 mid fbB<-B1(b0)
//           p2 post fa<-A1(b0);  p4 uses fbA (held)
//           p5 start fa<-A0(b1), fbB<-B0(b1);  p5 mid fbA<-B1(b1)
//           p6 post fa<-A1(b1);  p8 uses fbB (held)

#define GATE4 asm volatile("s_waitcnt vmcnt(4)" ::: "memory")
#define GATE0 asm volatile("s_waitcnt vmcnt(0)" ::: "memory")
#define GATEN
#define NOSTAGE
#define NORD

#define DSR(dst, base, imm) \
  asm volatile("ds_read_b128 %0, %1 offset:%2" : "=v"(dst) : "v"(base), "n"(imm))

#define RD_FA(BUF, H) { \
  DSR(fa0, rA00, (BUF)*32768 + (H)*16384 + 0); \
  DSR(fa1, rA01, (BUF)*32768 + (H)*16384 + 0); \
  DSR(fa2, rA00, (BUF)*32768 + (H)*16384 + 2048); \
  DSR(fa3, rA01, (BUF)*32768 + (H)*16384 + 2048); \
  DSR(fa4, rA00, (BUF)*32768 + (H)*16384 + 4096); \
  DSR(fa5, rA01, (BUF)*32768 + (H)*16384 + 4096); \
  DSR(fa6, rA00, (BUF)*32768 + (H)*16384 + 6144); \
  DSR(fa7, rA01, (BUF)*32768 + (H)*16384 + 6144); }

#define RD_FB_A(BUF, G) { \
  DSR(fbA0, rB00, (BUF)*32768 + (G)*16384 + 0); \
  DSR(fbA1, rB01, (BUF)*32768 + (G)*16384 + 0); \
  DSR(fbA2, rB00, (BUF)*32768 + (G)*16384 + 2048); \
  DSR(fbA3, rB01, (BUF)*32768 + (G)*16384 + 2048); }

#define RD_FB_B(BUF, G) { \
  DSR(fbB0, rB00, (BUF)*32768 + (G)*16384 + 0); \
  DSR(fbB1, rB01, (BUF)*32768 + (G)*16384 + 0); \
  DSR(fbB2, rB00, (BUF)*32768 + (G)*16384 + 2048); \
  DSR(fbB3, rB01, (BUF)*32768 + (G)*16384 + 2048); }

#define MFMA1(AI, Ax, Bx) \
  acc[AI] = __builtin_amdgcn_mfma_f32_16x16x32_f16(Ax, Bx, acc[AI], 0, 0, 0)

#define FBR(BN, i) fb##BN##i

#define STAGE_A(BUF, H, KD) { \
  gld16(stA + (BUF)*16384 + ((H)*128 +  0)*64, gAbase + (size_t)(((H)*64 +   0)*DIM) + (KD)); \
  gld16(stA + (BUF)*16384 + ((H)*128 + 64)*64, gAbase + (size_t)(((H)*64 + 128)*DIM) + (KD)); }

#define STAGE_B(BUF, G, KD) { \
  gld16(stB + (BUF)*16384 + ((G)*128 +  0)*64, gBbase + (size_t)(((G)*32 +   0)*DIM) + (KD)); \
  gld16(stB + (BUF)*16384 + ((G)*128 + 64)*64, gBbase + (size_t)(((G)*32 + 128)*DIM) + (KD)); }

#define PHASEX(H, G, BN, STARTRD, STAGE, MIDRD, GATE, POSTRD) { \
  STARTRD; \
  STAGE; \
  __builtin_amdgcn_s_barrier(); \
  asm volatile("s_waitcnt lgkmcnt(0)" ::: "memory"); \
  __builtin_amdgcn_sched_barrier(0); \
  __builtin_amdgcn_s_setprio(1); \
  MFMA1(((H)*4+0)*4 + (G)*2 + 0, fa0, FBR(BN,0)); \
  MFMA1(((H)*4+0)*4 + (G)*2 + 1, fa0, FBR(BN,2)); \
  MFMA1(((H)*4+1)*4 + (G)*2 + 0, fa2, FBR(BN,0)); \
  MFMA1(((H)*4+1)*4 + (G)*2 + 1, fa2, FBR(BN,2)); \
  MFMA1(((H)*4+2)*4 + (G)*2 + 0, fa4, FBR(BN,0)); \
  MFMA1(((H)*4+2)*4 + (G)*2 + 1, fa4, FBR(BN,2)); \
  MFMA1(((H)*4+3)*4 + (G)*2 + 0, fa6, FBR(BN,0)); \
  MFMA1(((H)*4+3)*4 + (G)*2 + 1, fa6, FBR(BN,2)); \
  __builtin_amdgcn_sched_barrier(0); \
  MIDRD; \
  __builtin_amdgcn_sched_barrier(0); \
  MFMA1(((H)*4+0)*4 + (G)*2 + 0, fa1, FBR(BN,1)); \
  MFMA1(((H)*4+0)*4 + (G)*2 + 1, fa1, FBR(BN,3)); \
  MFMA1(((H)*4+1)*4 + (G)*2 + 0, fa3, FBR(BN,1)); \
  MFMA1(((H)*4+1)*4 + (G)*2 + 1, fa3, FBR(BN,3)); \
  MFMA1(((H)*4+2)*4 + (G)*2 + 0, fa5, FBR(BN,1)); \
  MFMA1(((H)*4+2)*4 + (G)*2 + 1, fa5, FBR(BN,3)); \
  MFMA1(((H)*4+3)*4 + (G)*2 + 0, fa7, FBR(BN,1)); \
  MFMA1(((H)*4+3)*4 + (G)*2 + 1, fa7, FBR(BN,3)); \
  __builtin_amdgcn_s_setprio(0); \
  __builtin_amdgcn_sched_barrier(0); \
  GATE; \
  POSTRD; \
  __builtin_amdgcn_s_barrier(); }

__global__ __launch_bounds__(512, 2) void k1_s1(
    const half_t* __restrict__ Ahg, const half_t* __restrict__ Bhg,
    const float* __restrict__ zsq, unsigned int* __restrict__ runmin,
    int* __restrict__ cnt, int* __restrict__ list) {
  __shared__ __align__(16) half_t sA[2][256 * 64];   // 64 KB
  __shared__ __align__(16) half_t sB[2][256 * 64];   // 64 KB
  __shared__ float lzs[256];
  __shared__ float redD[256][4];
  __shared__ float lbound[256];

  const int tid = threadIdx.x;
  const int row0  = blockIdx.x * 256;
  const int code0 = blockIdx.y * 256;
  const int wave = tid >> 6, lane = tid & 63;
  const int wm = wave >> 2, wn = wave & 3;
  const int q = lane >> 4, l16 = lane & 15;
  const int sr = lane >> 3, ss = lane & 7;
  const int gsw8 = (ss ^ sr) * 8;
  const int s0 = wave * 8 + sr;                    // staging sub-row 0..63

  if (tid < 256) lzs[tid] = zsq[row0 + tid];

  // ---- hoisted LDS read bases (bytes, as3 addresses) ----
  const uint ldsA = (uint)(size_t)(lds_half_t*)&sA[0][0];
  const uint ldsB = (uint)(size_t)(lds_half_t*)&sB[0][0];
  const int xr = l16 & 7;
  const uint rA00 = ldsA + (uint)((wm * 64 + l16) * 128 + ((q ^ xr) * 16));
  const uint rA01 = ldsA + (uint)((wm * 64 + l16) * 128 + (((4 + q) ^ xr) * 16));
  const uint rB00 = ldsB + (uint)((wn * 32 + l16) * 128 + ((q ^ xr) * 16));
  const uint rB01 = ldsB + (uint)((wn * 32 + l16) * 128 + (((4 + q) ^ xr) * 16));

  // ---- hoisted staging bases ----
  half_t* stA = &sA[0][0] + s0 * 64 + ss * 8;
  half_t* stB = &sB[0][0] + s0 * 64 + ss * 8;
  const half_t* gAbase = Ahg + (size_t)(row0 + s0) * DIM + gsw8;
  const half_t* gBbase = Bhg + (size_t)(code0 + (s0 >> 5) * 64 + (s0 & 31)) * DIM + gsw8;

  // fragment register banks (read-once; B double-banked for mid-MFMA loads)
  half8 fa0, fa1, fa2, fa3, fa4, fa5, fa6, fa7;
  half8 fbA0, fbA1, fbA2, fbA3;
  half8 fbB0, fbB1, fbB2, fbB3;

  f32x4 acc[32];
  #pragma unroll
  for (int i = 0; i < 32; ++i) acc[i] = (f32x4){0.f, 0.f, 0.f, 0.f};

  // prologue: buf0 <- tile0 (A0,B1,A1,B0), buf1 early units <- tile1 (A0,B1)
  STAGE_A(0, 0, 0);  STAGE_B(0, 1, 0);  STAGE_A(0, 1, 0);  STAGE_B(0, 0, 0);
  STAGE_A(1, 0, 64); STAGE_B(1, 1, 64);
  GATE4;                                        // buf0 fully landed (allow 2 buf1 units)
  asm volatile("s_waitcnt lgkmcnt(0)" ::: "memory");  // lzs ds_write visible
  __builtin_amdgcn_s_barrier();

  for (int t = 0; t < 5; ++t) {
    const int kdB  = t * 128 + 64;   // buf1 current tile (late units A1,B0)
    const int kdN0 = t * 128 + 128;  // buf0 next tile
    const int kdN1 = t * 128 + 192;  // buf1 next tile (early units A0,B1)
    PHASEX(0, 0, A, { RD_FA(0,0); RD_FB_A(0,0); }, STAGE_A(1, 1, kdB),  RD_FB_B(0,1), GATEN, NORD);
    PHASEX(0, 1, B, NORD,                          STAGE_B(1, 0, kdB),  NORD,         GATEN, RD_FA(0,1));
    PHASEX(1, 1, B, NORD,                          STAGE_A(0, 0, kdN0), NORD,         GATEN, NORD);
    PHASEX(1, 0, A, NORD,                          STAGE_B(0, 1, kdN0), NORD,         GATE4, NORD);
    PHASEX(0, 0, B, { RD_FA(1,0); RD_FB_B(1,0); }, STAGE_A(0, 1, kdN0), RD_FB_A(1,1), GATEN, NORD);
    PHASEX(0, 1, A, NORD,                          STAGE_B(0, 0, kdN0), NORD,         GATEN, RD_FA(1,1));
    PHASEX(1, 1, A, NORD,                          STAGE_A(1, 0, kdN1), NORD,         GATEN, NORD);
    PHASEX(1, 0, B, NORD,                          STAGE_B(1, 1, kdN1), NORD,         GATE4, NORD);
  }
  { // tail iter t=5: only tile-11 late units remain to stage
    PHASEX(0, 0, A, { RD_FA(0,0); RD_FB_A(0,0); }, STAGE_A(1, 1, 704), RD_FB_B(0,1), GATEN, NORD);
    PHASEX(0, 1, B, NORD,                          STAGE_B(1, 0, 704), NORD,         GATEN, RD_FA(0,1));
    PHASEX(1, 1, B, NORD,                          NOSTAGE,            NORD,         GATEN, NORD);
    PHASEX(1, 0, A, NORD,                          NOSTAGE,            NORD,         GATE0, NORD);
    PHASEX(0, 0, B, { RD_FA(1,0); RD_FB_B(1,0); }, NOSTAGE,            RD_FB_A(1,1), GATEN, NORD);
    PHASEX(0, 1, A, NORD,                          NOSTAGE,            NORD,         GATEN, RD_FA(1,1));
    PHASEX(1, 1, A, NORD,                          NOSTAGE,            NORD,         GATEN, NORD);
    PHASEX(1, 0, B, NORD,                          NOSTAGE,            NORD,         GATEN, NORD);
  }

  // transform acc -> approx distance d~ = fl(zs - 2^-11 * acc)
  const float c2 = -4.8828125e-4f;   // -2^-11 (B prescaled by 4096)
  #pragma unroll
  for (int tm = 0; tm < 8; ++tm)
    #pragma unroll
    for (int reg = 0; reg < 4; ++reg) {
      const float zs = lzs[wm * 128 + tm * 16 + q * 4 + reg];
      #pragma unroll
      for (int tn = 0; tn < 4; ++tn)
        acc[tm * 4 + tn][reg] = fmaf(c2, acc[tm * 4 + tn][reg], zs);
    }

  // block-local per-row min
  #pragma unroll
  for (int tm = 0; tm < 8; ++tm)
    #pragma unroll
    for (int reg = 0; reg < 4; ++reg) {
      float m = acc[tm * 4 + 0][reg];
      #pragma unroll
      for (int tn = 1; tn < 4; ++tn) m = fminf(m, acc[tm * 4 + tn][reg]);
      #pragma unroll
      for (int off = 8; off; off >>= 1) m = fminf(m, __shfl_xor(m, off, 64));
      if (l16 == 0) redD[wm * 128 + tm * 16 + q * 4 + reg][wn] = m;
    }
  __syncthreads();
  if (tid < 256) {
    const float lm = fminf(fminf(redD[tid][0], redD[tid][1]),
                           fminf(redD[tid][2], redD[tid][3]));
    const unsigned rg = runmin[row0 + tid];          // stale-safe: always >= true min
    atomicMin(&runmin[row0 + tid], __float_as_uint(lm));
    lbound[tid] = fminf(lm, __uint_as_float(rg)) + DELTA;
  }
  __syncthreads();

  // collect candidates within margin (provably includes reference winner + ties)
  #pragma unroll
  for (int tm = 0; tm < 8; ++tm)
    #pragma unroll
    for (int reg = 0; reg < 4; ++reg) {
      const int row_b = wm * 128 + tm * 16 + q * 4 + reg;
      const float b = lbound[row_b];
      #pragma unroll
      for (int tn = 0; tn < 4; ++tn) {
        const float d = acc[tm * 4 + tn][reg];
        if (d <= b) {
          const int grow = row0 + row_b;
          const int pos = atomicAdd(&cnt[grow], 1);
          if (pos < CAP) list[(size_t)grow * CAP + pos] = code0 + wn * 64 + tn * 16 + l16;
        }
      }
    }
}

// ---- k_refine: fp64 re-score of survivors + gather + STE + loss (fused) ---
__global__ void k_refine(const float* __restrict__ z, const float* __restrict__ cb,
                         const float* __restrict__ zsq, const int* __restrict__ cnt,
                         const int* __restrict__ list, float* __restrict__ out_codes,
                         float* __restrict__ outq, double* __restrict__ loss) {
  const int r = blockIdx.x;
  const int tid = threadIdx.x, wave = tid >> 6, lane = tid & 63;
  __shared__ unsigned long long wbest[4];
  __shared__ double wsum[4];
  __shared__ int sidx;
  __shared__ __align__(16) float zsh[DIM];

  if (tid < DIM / 4) ((float4*)zsh)[tid] = ((const float4*)(z + (size_t)r * DIM))[tid];
  __syncthreads();

  int n = cnt[r]; if (n > CAP) n = CAP;
  const bool empty = (n == 0); if (empty) n = 1;   // winner provably collected; guard anyway
  const double zsd = (double)zsq[r];
  unsigned long long best = ~0ull;
  for (int ci = wave; ci < n; ci += 4) {
    const int idx = empty ? 0 : list[(size_t)r * CAP + ci];
    const float4* cr = (const float4*)(cb + (size_t)idx * DIM);
    double s = 0.0;
    #pragma unroll
    for (int p = 0; p < 3; ++p) {
      const float4 cv = cr[lane + p * 64];
      const float4 zv = ((const float4*)zsh)[lane + p * 64];
      s += (double)zv.x * cv.x + (double)zv.y * cv.y +
           (double)zv.z * cv.z + (double)zv.w * cv.w;
    }
    #pragma unroll
    for (int off = 32; off; off >>= 1) s += __shfl_xor(s, off, 64);
    const float d = (float)(zsd - 2.0 * s);        // single rounding, ref semantics
    const unsigned long long key =
        ((unsigned long long)__float_as_uint(d) << 32) | (unsigned)idx;
    if (key < best) best = key;                    // (d, idx) lexicographic
  }
  if (lane == 0) wbest[wave] = best;
  __syncthreads();
  if (tid == 0) {
    unsigned long long b = wbest[0];
    #pragma unroll
    for (int w = 1; w < 4; ++w) if (wbest[w] < b) b = wbest[w];
    const int idx = (int)(unsigned)(b & 0xffffffffull);
    sidx = idx;
    out_codes[r] = (float)idx;
  }
  __syncthreads();

  const int c = sidx;
  double ls = 0.0;
  #pragma unroll
  for (int j = 0; j < 3; ++j) {
    const int e = tid + j * 256;
    const float qx = cb[(size_t)c * DIM + e];
    const float zx = zsh[e];
    const float dd = qx - zx;
    outq[(size_t)r * DIM + e] = zx + dd;           // fl(z + fl(q-z)) bitwise
    ls += (double)dd * (double)dd;
  }
  #pragma unroll
  for (int off = 32; off; off >>= 1) ls += __shfl_xor(ls, off, 64);
  if (lane == 0) wsum[wave] = ls;
  __syncthreads();
  if (tid == 0) atomicAdd(loss, wsum[0] + wsum[1] + wsum[2] + wsum[3]);
}

// ---- k4: finalize loss -----------------------------------------------------
__global__ void k4_final(const double* __restrict__ loss, float* __restrict__ out) {
  float m = (float)(*loss / ((double)NROWS * (double)DIM));
  out[0] = m + 0.25f * m;
}

// ======================= fallback path (ws too small) =======================
__global__ void k0_zsq(const float* __restrict__ z, float* __restrict__ zsq,
                       unsigned long long* __restrict__ keys, double* __restrict__ loss) {
  const int wave = threadIdx.x >> 6, lane = threadIdx.x & 63;
  const int row = blockIdx.x * 4 + wave;
  const float* zr = z + (size_t)row * DIM;
  float s = 0.f;
  #pragma unroll
  for (int i = 0; i < DIM / 64; ++i) { float v = zr[lane + i * 64]; s = fmaf(v, v, s); }
  #pragma unroll
  for (int off = 32; off; off >>= 1) s += __shfl_xor(s, off, 64);
  if (lane == 0) zsq[row] = s;
  const int gid = blockIdx.x * 256 + threadIdx.x;
  if (gid < NROWS) keys[gid] = ~0ull;
  if (gid == 0) *loss = 0.0;
}

__global__ __launch_bounds__(256, 2) void k1_mfma(
    const float* __restrict__ z, const float* __restrict__ cb,
    const float* __restrict__ zsq, unsigned long long* __restrict__ keys) {
  __shared__ half_t Ah[TM * SA], Al[TM * SA], Bh[TC * SA], Bl[TC * SA];
  __shared__ float lzs[TM];
  __shared__ float redD[TM][2];
  __shared__ int   redI[TM][2];

  const int tid  = threadIdx.x;
  const int row0  = blockIdx.x * TM;
  const int code0 = blockIdx.y * TC;
  const int wave = tid >> 6, lane = tid & 63;
  const int wm = wave & 1, wn = wave >> 1;
  const int q = lane >> 4, l16 = lane & 15;

  if (tid < TM) lzs[tid] = zsq[row0 + tid];

  const int srow = tid >> 2;
  const int sko  = (tid & 3) * 8;

  f32x4 acc0[16], acc1[16];
  #pragma unroll
  for (int i = 0; i < 16; ++i) {
    acc0[i] = (f32x4){0.f, 0.f, 0.f, 0.f};
    acc1[i] = (f32x4){0.f, 0.f, 0.f, 0.f};
  }

  const float* zp = z  + (size_t)row0  * DIM;
  const float* bp = cb + (size_t)code0 * DIM;

  for (int kd = 0; kd < DIM; kd += 32) {
    __syncthreads();
    #pragma unroll
    for (int s = 0; s < 2; ++s) {
      const int r = srow + s * 64;
      const float* srca = zp + (size_t)r * DIM + kd + sko;
      float4 v0 = *(const float4*)srca;
      float4 v1 = *(const float4*)(srca + 4);
      float a[8] = {v0.x, v0.y, v0.z, v0.w, v1.x, v1.y, v1.z, v1.w};
      half8 hi, lo;
      #pragma unroll
      for (int j = 0; j < 8; ++j) {
        half_t h = (half_t)a[j];
        hi[j] = h;
        lo[j] = (half_t)((a[j] - (float)h) * 4096.f);
      }
      *(half8*)&Ah[r * SA + sko] = hi;
      *(half8*)&Al[r * SA + sko] = lo;
      const float* srcb = bp + (size_t)r * DIM + kd + sko;
      v0 = *(const float4*)srcb; v1 = *(const float4*)(srcb + 4);
      float b[8] = {v0.x, v0.y, v0.z, v0.w, v1.x, v1.y, v1.z, v1.w};
      #pragma unroll
      for (int j = 0; j < 8; ++j) {
        float bs = b[j] * 4096.f;
        half_t h = (half_t)bs;
        hi[j] = h;
        lo[j] = (half_t)((bs - (float)h) * 4096.f);
      }
      *(half8*)&Bh[r * SA + sko] = hi;
      *(half8*)&Bl[r * SA + sko] = lo;
    }
    __syncthreads();

    half8 fa_h[4], fa_l[4], fb_h[4], fb_l[4];
    #pragma unroll
    for (int t = 0; t < 4; ++t) {
      const int ar = (wm * 64 + t * 16 + l16) * SA + q * 8;
      fa_h[t] = *(const half8*)&Ah[ar];
      fa_l[t] = *(const half8*)&Al[ar];
      const int br = (wn * 64 + t * 16 + l16) * SA + q * 8;
      fb_h[t] = *(const half8*)&Bh[br];
      fb_l[t] = *(const half8*)&Bl[br];
    }
    #pragma unroll
    for (int tm = 0; tm < 4; ++tm)
      #pragma unroll
      for (int tn = 0; tn < 4; ++tn) {
        const int i = tm * 4 + tn;
        acc0[i] = __builtin_amdgcn_mfma_f32_16x16x32_f16(fa_h[tm], fb_h[tn], acc0[i], 0, 0, 0);
        acc1[i] = __builtin_amdgcn_mfma_f32_16x16x32_f16(fa_l[tm], fb_h[tn], acc1[i], 0, 0, 0);
        acc1[i] = __builtin_amdgcn_mfma_f32_16x16x32_f16(fa_h[tm], fb_l[tn], acc1[i], 0, 0, 0);
      }
  }

  const float c1 = 2.44140625e-4f;
  const float c2 = -4.8828125e-4f;
  #pragma unroll
  for (int tm = 0; tm < 4; ++tm) {
    #pragma unroll
    for (int reg = 0; reg < 4; ++reg) {
      const int row_b = wm * 64 + tm * 16 + q * 4 + reg;
      const float zs = lzs[row_b];
      float bd = FLT_MAX; int bi = 0x7fffffff;
      #pragma unroll
      for (int tn = 0; tn < 4; ++tn) {
        const int i = tm * 4 + tn;
        float v = fmaf(c1, acc1[i][reg], acc0[i][reg]);
        float d = fmaf(c2, v, zs);
        const int ci = code0 + wn * 64 + tn * 16 + l16;
        if (d < bd || (d == bd && ci < bi)) { bd = d; bi = ci; }
      }
      #pragma unroll
      for (int off = 8; off; off >>= 1) {
        float od = __shfl_xor(bd, off, 64);
        int   oi = __shfl_xor(bi, off, 64);
        if (od < bd || (od == bd && oi < bi)) { bd = od; bi = oi; }
      }
      if (l16 == 0) { redD[row_b][wn] = bd; redI[row_b][wn] = bi; }
    }
  }
  __syncthreads();
  if (tid < TM) {
    float d0 = redD[tid][0]; int i0 = redI[tid][0];
    float d1 = redD[tid][1]; int i1 = redI[tid][1];
    if (d1 < d0 || (d1 == d0 && i1 < i0)) { d0 = d1; i0 = i1; }
    unsigned long long key = ((unsigned long long)__float_as_uint(d0) << 32) | (unsigned int)i0;
    atomicMin(&keys[row0 + tid], key);
  }
}

__global__ void k2_codes(const unsigned long long* __restrict__ keys,
                         float* __restrict__ out_codes, int* __restrict__ codes_i) {
  const int r = blockIdx.x * 256 + threadIdx.x;
  const int idx = (int)(unsigned int)(keys[r] & 0xffffffffull);
  out_codes[r] = (float)idx;
  codes_i[r] = idx;
}

__global__ void k3_quant_loss(const float* __restrict__ z, const float* __restrict__ cb,
                              const int* __restrict__ codes, float* __restrict__ outq,
                              double* __restrict__ loss) {
  const int gid = blockIdx.x * blockDim.x + threadIdx.x;
  const int e0 = gid * 4;
  const int row = e0 / DIM;
  const int col = e0 - row * DIM;
  const int c = codes[row];
  const float4 zv = *(const float4*)(z + e0);
  const float4 qv = *(const float4*)(cb + (size_t)c * DIM + col);
  float d0 = qv.x - zv.x, d1 = qv.y - zv.y, d2 = qv.z - zv.z, d3 = qv.w - zv.w;
  float4 ov = { zv.x + d0, zv.y + d1, zv.z + d2, zv.w + d3 };
  *(float4*)(outq + e0) = ov;
  double s = (double)(d0 * d0) + (double)(d1 * d1) + (double)(d2 * d2) + (double)(d3 * d3);
  #pragma unroll
  for (int off = 32; off; off >>= 1) s += __shfl_xor(s, off, 64);
  __shared__ double wsum[4];
  const int wave = threadIdx.x >> 6, lane = threadIdx.x & 63;
  if (lane == 0) wsum[wave] = s;
  __syncthreads();
  if (threadIdx.x == 0) atomicAdd(loss, wsum[0] + wsum[1] + wsum[2] + wsum[3]);
}

extern "C" void kernel_launch(void* const* d_in, const int* in_sizes, int n_in,
                              void* d_out, int out_size, void* d_ws, size_t ws_size,
                              hipStream_t stream) {
  const float* z  = (const float*)d_in[0];
  const float* cb = (const float*)d_in[1];
  float* out = (float*)d_out;          // [codes 4096][q_ste 3145728][loss 1]
  char* ws = (char*)d_ws;
  float*  zsq = (float*)(ws + WS_ZSQ);
  unsigned int* runmin = (unsigned int*)(ws + WS_RUNMIN);
  int* cnt     = (int*)(ws + WS_CNT);
  int* codes_i = (int*)(ws + WS_CODESI);
  double* loss = (double*)(ws + WS_LOSS);
  int* list    = (int*)(ws + WS_LIST);
  unsigned long long* keys = (unsigned long long*)(ws + WS_LIST);

  if (ws_size >= WS_NEED) {
    half_t* Ahg = (half_t*)(ws + WS_AH);
    half_t* Bhg = (half_t*)(ws + WS_BH);
    dim3 g1s(NROWS / 256, KCODES / 256);
    k_convA<<<NROWS / 4, 256, 0, stream>>>(z, Ahg, zsq, runmin, cnt, loss);
    k_convB<<<(KCODES * DIM / 8 + 255) / 256, 256, 0, stream>>>(cb, Bhg, KCODES * DIM / 8);
    k1_s1<<<g1s, 512, 0, stream>>>(Ahg, Bhg, zsq, runmin, cnt, list);
    k_refine<<<NROWS, 256, 0, stream>>>(z, cb, zsq, cnt, list, out, out + NROWS, loss);
  } else {
    dim3 g1(NROWS / TM, KCODES / TC);
    k0_zsq<<<NROWS / 4, 256, 0, stream>>>(z, zsq, keys, loss);
    k1_mfma<<<g1, 256, 0, stream>>>(z, cb, zsq, keys);
    k2_codes<<<NROWS / 256, 256, 0, stream>>>(keys, out, codes_i);
    k3_quant_loss<<<(NROWS * DIM / 4) / 256, 256, 0, stream>>>(z, cb, codes_i, out + NROWS, loss);
  }

  k4_final<<<1, 1, 0, stream>>>(loss, out + NROWS + (size_t)NROWS * DIM);
}

// Round 5
// 938.174 us; speedup vs baseline: 1.1392x; 1.0074x over previous
//
#include <hip/hip_runtime.h>
#include <cfloat>
#include <cstdint>

#define NROWS  4096
#define DIM    768
#define KCODES 65536

#define TM 128
#define TC 128
#define BK 64          // K-chunk (halves); 128-B LDS row stride (r3-verified swizzle geometry)
#define SA 40          // fallback path LDS stride
#define CAP 2048       // candidate list slots per row
#define DELTA 3.0e-4f  // guaranteed screening margin (worst-case err chain ~1.6e-4)

// workspace layout (bytes)
#define WS_ZSQ    0                          // 4096 f32
#define WS_RUNMIN 16384                      // 4096 u32
#define WS_CNT    32768                      // 4096 i32
#define WS_CODESI 49152                      // 4096 i32 (fallback)
#define WS_LOSS   65536                      // 1 f64
#define WS_LIST   131072                     // 4096*CAP i32 = 32 MB (fallback: keys u64)
#define WS_AH     (WS_LIST + (size_t)NROWS*CAP*4)
#define WS_BH     (WS_AH + (size_t)NROWS*DIM*2)
#define WS_NEED   (WS_BH + (size_t)KCODES*DIM*2)

typedef _Float16 half_t;
typedef _Float16 half4 __attribute__((ext_vector_type(4)));
typedef _Float16 half8 __attribute__((ext_vector_type(8)));
typedef float    f32x4 __attribute__((ext_vector_type(4)));
typedef unsigned int uint;
typedef __attribute__((address_space(3))) half_t lds_half_t;

__device__ __forceinline__ void gld16(half_t* lds, const half_t* g) {
  __builtin_amdgcn_global_load_lds(
      (const __attribute__((address_space(1))) unsigned int*)g,
      (__attribute__((address_space(3))) unsigned int*)lds, 16, 0, 0);
}

// ---- k_convA: z -> fp16 hi, z_sq per row, init runmin/cnt, zero loss ------
__global__ void k_convA(const float* __restrict__ z, half_t* __restrict__ h,
                        float* __restrict__ zsq, unsigned int* __restrict__ runmin,
                        int* __restrict__ cnt, double* __restrict__ loss) {
  const int wave = threadIdx.x >> 6, lane = threadIdx.x & 63;
  const int row = blockIdx.x * 4 + wave;
  const float4* zr = (const float4*)(z + (size_t)row * DIM);
  half_t* hr = h + (size_t)row * DIM;
  float s = 0.f;
  #pragma unroll
  for (int p = 0; p < 3; ++p) {
    float4 v = zr[lane + p * 64];
    s = fmaf(v.x, v.x, s); s = fmaf(v.y, v.y, s);
    s = fmaf(v.z, v.z, s); s = fmaf(v.w, v.w, s);
    half4 hv = { (half_t)v.x, (half_t)v.y, (half_t)v.z, (half_t)v.w };
    *(half4*)(hr + (lane + p * 64) * 4) = hv;
  }
  #pragma unroll
  for (int off = 32; off; off >>= 1) s += __shfl_xor(s, off, 64);
  if (lane == 0) zsq[row] = s;
  const int gid = blockIdx.x * 256 + threadIdx.x;
  if (gid < NROWS) { runmin[gid] = 0x7f7fffffu; cnt[gid] = 0; }
  if (gid == 0) *loss = 0.0;
}

// ---- k_convB: cb -> fp16 hi, prescaled by 4096 ----------------------------
__global__ void k_convB(const float* __restrict__ src, half_t* __restrict__ h, int n8) {
  const int i = blockIdx.x * 256 + threadIdx.x;
  if (i >= n8) return;
  float4 v0 = ((const float4*)src)[2 * i];
  float4 v1 = ((const float4*)src)[2 * i + 1];
  float a[8] = {v0.x, v0.y, v0.z, v0.w, v1.x, v1.y, v1.z, v1.w};
  half8 hi;
  #pragma unroll
  for (int j = 0; j < 8; ++j) hi[j] = (half_t)(a[j] * 4096.f);
  ((half8*)h)[i] = hi;
}

// ---- k1_s1: 256x256-tile 8-phase fp16 MFMA screen + candidate collection --
// v5: same verified staging/dataflow as v1-v4 (absmax=0 x4); LDS reads now a
// uniform 1-phase-ahead pipeline:
//   - cluster1 (slice0, even regs) -> MID: read NEXT phase's slice0 into the
//     just-freed even regs -> cluster2 (slice1, odd) -> POST: slice1 reads.
//     Every phase's MFMA uses regs loaded >= half a phase earlier.
//   - GATE4 moved to p4/p8 START (before opening barrier): retires exactly
//     {p7',p8',p1,p2} / {p3..p6}, so p4/p8-MID can read the next half-buffer
//     (all-waves safety = own gate + barrier). Gate arithmetic unchanged.
//   - audited: every stage/overwrite >= 2 barriers after its region's last
//     LDS read; every read gate-retired + barrier-published before issue.
//   - acc accumulation order (s0 then s1 per phase) identical -> bitwise same.
//
// Read->stage deps (read phase X needs stage Y, prev iter unless marked):
//   p1: A0@p3', B0@p6'   p2: B1@p4'   p3: A1@p5' (read p2-mid)
//   p4-mid: A0(b1)@p7', B0(b1)@p2(this)   p5: B1(b1)@p8'   p6: A1(b1)@p1(this)
//   gates: p4 GATE4 retires p7',p8',p1,p2 ; p8 GATE4 retires p3..p6.

#define GATE4 asm volatile("s_waitcnt vmcnt(4)" ::: "memory")
#define GATE0 asm volatile("s_waitcnt vmcnt(0)" ::: "memory")
#define NOSTAGE
#define NORD

#define DSR(dst, base, imm) \
  asm volatile("ds_read_b128 %0, %1 offset:%2" : "=v"(dst) : "v"(base), "n"(imm))

// A fragment reads: slice0 -> even regs (rA00), slice1 -> odd (rA01)
#define RDA_S0(BUF, H) { \
  DSR(fa0, rA00, (BUF)*32768 + (H)*16384 + 0); \
  DSR(fa2, rA00, (BUF)*32768 + (H)*16384 + 2048); \
  DSR(fa4, rA00, (BUF)*32768 + (H)*16384 + 4096); \
  DSR(fa6, rA00, (BUF)*32768 + (H)*16384 + 6144); }
#define RDA_S1(BUF, H) { \
  DSR(fa1, rA01, (BUF)*32768 + (H)*16384 + 0); \
  DSR(fa3, rA01, (BUF)*32768 + (H)*16384 + 2048); \
  DSR(fa5, rA01, (BUF)*32768 + (H)*16384 + 4096); \
  DSR(fa7, rA01, (BUF)*32768 + (H)*16384 + 6144); }

// B fragment reads into bank BK (0/1, keyed by G): idx = n*2+slice
#define RDB_S0(BK, BUF, GU) { \
  DSR(bg##BK##0, rB00, (BUF)*32768 + (GU)*16384 + 0); \
  DSR(bg##BK##2, rB00, (BUF)*32768 + (GU)*16384 + 2048); }
#define RDB_S1(BK, BUF, GU) { \
  DSR(bg##BK##1, rB01, (BUF)*32768 + (GU)*16384 + 0); \
  DSR(bg##BK##3, rB01, (BUF)*32768 + (GU)*16384 + 2048); }

#define MFMA1(AI, Ax, Bx) \
  acc[AI] = __builtin_amdgcn_mfma_f32_16x16x32_f16(Ax, Bx, acc[AI], 0, 0, 0)

#define CL1(H, G) \
  MFMA1(((H)*4+0)*4 + (G)*2 + 0, fa0, bg##G##0); \
  MFMA1(((H)*4+0)*4 + (G)*2 + 1, fa0, bg##G##2); \
  MFMA1(((H)*4+1)*4 + (G)*2 + 0, fa2, bg##G##0); \
  MFMA1(((H)*4+1)*4 + (G)*2 + 1, fa2, bg##G##2); \
  MFMA1(((H)*4+2)*4 + (G)*2 + 0, fa4, bg##G##0); \
  MFMA1(((H)*4+2)*4 + (G)*2 + 1, fa4, bg##G##2); \
  MFMA1(((H)*4+3)*4 + (G)*2 + 0, fa6, bg##G##0); \
  MFMA1(((H)*4+3)*4 + (G)*2 + 1, fa6, bg##G##2);

#define CL2(H, G) \
  MFMA1(((H)*4+0)*4 + (G)*2 + 0, fa1, bg##G##1); \
  MFMA1(((H)*4+0)*4 + (G)*2 + 1, fa1, bg##G##3); \
  MFMA1(((H)*4+1)*4 + (G)*2 + 0, fa3, bg##G##1); \
  MFMA1(((H)*4+1)*4 + (G)*2 + 1, fa3, bg##G##3); \
  MFMA1(((H)*4+2)*4 + (G)*2 + 0, fa5, bg##G##1); \
  MFMA1(((H)*4+2)*4 + (G)*2 + 1, fa5, bg##G##3); \
  MFMA1(((H)*4+3)*4 + (G)*2 + 0, fa7, bg##G##1); \
  MFMA1(((H)*4+3)*4 + (G)*2 + 1, fa7, bg##G##3);

#define STAGE_A(BUF, H, KD) { \
  gld16(stA + (BUF)*16384 + ((H)*128 +  0)*64, gAbase + (size_t)(((H)*64 +   0)*DIM) + (KD)); \
  gld16(stA + (BUF)*16384 + ((H)*128 + 64)*64, gAbase + (size_t)(((H)*64 + 128)*DIM) + (KD)); }

#define STAGE_B(BUF, G, KD) { \
  gld16(stB + (BUF)*16384 + ((G)*128 +  0)*64, gBbase + (size_t)(((G)*32 +   0)*DIM) + (KD)); \
  gld16(stB + (BUF)*16384 + ((G)*128 + 64)*64, gBbase + (size_t)(((G)*32 + 128)*DIM) + (KD)); }

#define PHASE(H, G, PRE, MID, POST) { \
  PRE; \
  __builtin_amdgcn_s_barrier(); \
  asm volatile("s_waitcnt lgkmcnt(0)" ::: "memory"); \
  __builtin_amdgcn_sched_barrier(0); \
  __builtin_amdgcn_s_setprio(1); \
  CL1(H, G); \
  __builtin_amdgcn_sched_barrier(0); \
  MID; \
  __builtin_amdgcn_sched_barrier(0); \
  CL2(H, G); \
  __builtin_amdgcn_s_setprio(0); \
  __builtin_amdgcn_sched_barrier(0); \
  POST; \
  __builtin_amdgcn_s_barrier(); }

__global__ __launch_bounds__(512, 2) void k1_s1(
    const half_t* __restrict__ Ahg, const half_t* __restrict__ Bhg,
    const float* __restrict__ zsq, unsigned int* __restrict__ runmin,
    int* __restrict__ cnt, int* __restrict__ list) {
  __shared__ __align__(16) half_t sA[2][256 * 64];   // 64 KB
  __shared__ __align__(16) half_t sB[2][256 * 64];   // 64 KB
  __shared__ float lzs[256];
  __shared__ float redD[256][4];
  __shared__ float lbound[256];

  const int tid = threadIdx.x;
  const int row0  = blockIdx.x * 256;
  const int code0 = blockIdx.y * 256;
  const int wave = tid >> 6, lane = tid & 63;
  const int wm = wave >> 2, wn = wave & 3;
  const int q = lane >> 4, l16 = lane & 15;
  const int sr = lane >> 3, ss = lane & 7;
  const int gsw8 = (ss ^ sr) * 8;
  const int s0 = wave * 8 + sr;                    // staging sub-row 0..63

  if (tid < 256) lzs[tid] = zsq[row0 + tid];

  // ---- hoisted LDS read bases (bytes, as3 addresses) ----
  const uint ldsA = (uint)(size_t)(lds_half_t*)&sA[0][0];
  const uint ldsB = (uint)(size_t)(lds_half_t*)&sB[0][0];
  const int xr = l16 & 7;
  const uint rA00 = ldsA + (uint)((wm * 64 + l16) * 128 + ((q ^ xr) * 16));
  const uint rA01 = ldsA + (uint)((wm * 64 + l16) * 128 + (((4 + q) ^ xr) * 16));
  const uint rB00 = ldsB + (uint)((wn * 32 + l16) * 128 + ((q ^ xr) * 16));
  const uint rB01 = ldsB + (uint)((wn * 32 + l16) * 128 + (((4 + q) ^ xr) * 16));

  // ---- hoisted staging bases ----
  half_t* stA = &sA[0][0] + s0 * 64 + ss * 8;
  half_t* stB = &sB[0][0] + s0 * 64 + ss * 8;
  const half_t* gAbase = Ahg + (size_t)(row0 + s0) * DIM + gsw8;
  const half_t* gBbase = Bhg + (size_t)(code0 + (s0 >> 5) * 64 + (s0 & 31)) * DIM + gsw8;

  // fragment register banks (read-once; even=slice0, odd=slice1; B keyed by G)
  half8 fa0, fa1, fa2, fa3, fa4, fa5, fa6, fa7;
  half8 bg00, bg01, bg02, bg03;
  half8 bg10, bg11, bg12, bg13;

  f32x4 acc[32];
  #pragma unroll
  for (int i = 0; i < 32; ++i) acc[i] = (f32x4){0.f, 0.f, 0.f, 0.f};

  // prologue: buf0 <- tile0 (A0,B1,A1,B0), buf1 early units <- tile1 (A0,B1)
  STAGE_A(0, 0, 0);  STAGE_B(0, 1, 0);  STAGE_A(0, 1, 0);  STAGE_B(0, 0, 0);
  STAGE_A(1, 0, 64); STAGE_B(1, 1, 64);
  GATE4;                                        // buf0 fully landed (leftover = buf1.{A0,B1})
  asm volatile("s_waitcnt lgkmcnt(0)" ::: "memory");  // lzs ds_write visible
  __builtin_amdgcn_s_barrier();
  // pre-read p1's banks: fa <- A0(b0), bg0 <- B0(b0)
  RDA_S0(0, 0); RDA_S1(0, 0); RDB_S0(0, 0, 0); RDB_S1(0, 0, 0);

  for (int t = 0; t < 5; ++t) {
    const int kdB  = t * 128 + 64;   // buf1 current tile (late units A1,B0)
    const int kdN0 = t * 128 + 128;  // buf0 next tile
    const int kdN1 = t * 128 + 192;  // buf1 next tile (early units A0,B1)
    PHASE(0, 0, STAGE_A(1, 1, kdB),               { RDB_S0(1,0,1); },               { RDB_S1(1,0,1); });
    PHASE(0, 1, STAGE_B(1, 0, kdB),               { RDA_S0(0,1); },                 { RDA_S1(0,1); });
    PHASE(1, 1, STAGE_A(0, 0, kdN0),              NORD,                             NORD);
    PHASE(1, 0, { STAGE_B(0, 1, kdN0); GATE4; },  { RDA_S0(1,0); RDB_S0(0,1,0); },  { RDA_S1(1,0); RDB_S1(0,1,0); });
    PHASE(0, 0, STAGE_A(0, 1, kdN0),              { RDB_S0(1,1,1); },               { RDB_S1(1,1,1); });
    PHASE(0, 1, STAGE_B(0, 0, kdN0),              { RDA_S0(1,1); },                 { RDA_S1(1,1); });
    PHASE(1, 1, STAGE_A(1, 0, kdN1),              NORD,                             NORD);
    PHASE(1, 0, { STAGE_B(1, 1, kdN1); GATE4; },  { RDA_S0(0,0); RDB_S0(0,0,0); },  { RDA_S1(0,0); RDB_S1(0,0,0); });
  }
  { // tail iter t=5 (tiles 10,11): only tile-11 late units remain to stage
    PHASE(0, 0, STAGE_A(1, 1, 704),               { RDB_S0(1,0,1); },               { RDB_S1(1,0,1); });
    PHASE(0, 1, STAGE_B(1, 0, 704),               { RDA_S0(0,1); },                 { RDA_S1(0,1); });
    PHASE(1, 1, NOSTAGE,                          NORD,                             NORD);
    PHASE(1, 0, GATE0,                            { RDA_S0(1,0); RDB_S0(0,1,0); },  { RDA_S1(1,0); RDB_S1(0,1,0); });
    PHASE(0, 0, NOSTAGE,                          { RDB_S0(1,1,1); },               { RDB_S1(1,1,1); });
    PHASE(0, 1, NOSTAGE,                          { RDA_S0(1,1); },                 { RDA_S1(1,1); });
    PHASE(1, 1, NOSTAGE,                          NORD,                             NORD);
    PHASE(1, 0, NOSTAGE,                          NORD,                             NORD);
  }

  // transform acc -> approx distance d~ = fl(zs - 2^-11 * acc)
  const float c2 = -4.8828125e-4f;   // -2^-11 (B prescaled by 4096)
  #pragma unroll
  for (int tm = 0; tm < 8; ++tm)
    #pragma unroll
    for (int reg = 0; reg < 4; ++reg) {
      const float zs = lzs[wm * 128 + tm * 16 + q * 4 + reg];
      #pragma unroll
      for (int tn = 0; tn < 4; ++tn)
        acc[tm * 4 + tn][reg] = fmaf(c2, acc[tm * 4 + tn][reg], zs);
    }

  // block-local per-row min
  #pragma unroll
  for (int tm = 0; tm < 8; ++tm)
    #pragma unroll
    for (int reg = 0; reg < 4; ++reg) {
      float m = acc[tm * 4 + 0][reg];
      #pragma unroll
      for (int tn = 1; tn < 4; ++tn) m = fminf(m, acc[tm * 4 + tn][reg]);
      #pragma unroll
      for (int off = 8; off; off >>= 1) m = fminf(m, __shfl_xor(m, off, 64));
      if (l16 == 0) redD[wm * 128 + tm * 16 + q * 4 + reg][wn] = m;
    }
  __syncthreads();
  if (tid < 256) {
    const float lm = fminf(fminf(redD[tid][0], redD[tid][1]),
                           fminf(redD[tid][2], redD[tid][3]));
    const unsigned rg = runmin[row0 + tid];          // stale-safe: always >= true min
    atomicMin(&runmin[row0 + tid], __float_as_uint(lm));
    lbound[tid] = fminf(lm, __uint_as_float(rg)) + DELTA;
  }
  __syncthreads();

  // collect candidates within margin (provably includes reference winner + ties)
  #pragma unroll
  for (int tm = 0; tm < 8; ++tm)
    #pragma unroll
    for (int reg = 0; reg < 4; ++reg) {
      const int row_b = wm * 128 + tm * 16 + q * 4 + reg;
      const float b = lbound[row_b];
      #pragma unroll
      for (int tn = 0; tn < 4; ++tn) {
        const float d = acc[tm * 4 + tn][reg];
        if (d <= b) {
          const int grow = row0 + row_b;
          const int pos = atomicAdd(&cnt[grow], 1);
          if (pos < CAP) list[(size_t)grow * CAP + pos] = code0 + wn * 64 + tn * 16 + l16;
        }
      }
    }
}

// ---- k_refine: fp64 re-score of survivors + gather + STE + loss (fused) ---
__global__ void k_refine(const float* __restrict__ z, const float* __restrict__ cb,
                         const float* __restrict__ zsq, const int* __restrict__ cnt,
                         const int* __restrict__ list, float* __restrict__ out_codes,
                         float* __restrict__ outq, double* __restrict__ loss) {
  const int r = blockIdx.x;
  const int tid = threadIdx.x, wave = tid >> 6, lane = tid & 63;
  __shared__ unsigned long long wbest[4];
  __shared__ double wsum[4];
  __shared__ int sidx;
  __shared__ __align__(16) float zsh[DIM];

  if (tid < DIM / 4) ((float4*)zsh)[tid] = ((const float4*)(z + (size_t)r * DIM))[tid];
  __syncthreads();

  int n = cnt[r]; if (n > CAP) n = CAP;
  const bool empty = (n == 0); if (empty) n = 1;   // winner provably collected; guard anyway
  const double zsd = (double)zsq[r];
  unsigned long long best = ~0ull;
  for (int ci = wave; ci < n; ci += 4) {
    const int idx = empty ? 0 : list[(size_t)r * CAP + ci];
    const float4* cr = (const float4*)(cb + (size_t)idx * DIM);
    double s = 0.0;
    #pragma unroll
    for (int p = 0; p < 3; ++p) {
      const float4 cv = cr[lane + p * 64];
      const float4 zv = ((const float4*)zsh)[lane + p * 64];
      s += (double)zv.x * cv.x + (double)zv.y * cv.y +
           (double)zv.z * cv.z + (double)zv.w * cv.w;
    }
    #pragma unroll
    for (int off = 32; off; off >>= 1) s += __shfl_xor(s, off, 64);
    const float d = (float)(zsd - 2.0 * s);        // single rounding, ref semantics
    const unsigned long long key =
        ((unsigned long long)__float_as_uint(d) << 32) | (unsigned)idx;
    if (key < best) best = key;                    // (d, idx) lexicographic
  }
  if (lane == 0) wbest[wave] = best;
  __syncthreads();
  if (tid == 0) {
    unsigned long long b = wbest[0];
    #pragma unroll
    for (int w = 1; w < 4; ++w) if (wbest[w] < b) b = wbest[w];
    const int idx = (int)(unsigned)(b & 0xffffffffull);
    sidx = idx;
    out_codes[r] = (float)idx;
  }
  __syncthreads();

  const int c = sidx;
  double ls = 0.0;
  #pragma unroll
  for (int j = 0; j < 3; ++j) {
    const int e = tid + j * 256;
    const float qx = cb[(size_t)c * DIM + e];
    const float zx = zsh[e];
    const float dd = qx - zx;
    outq[(size_t)r * DIM + e] = zx + dd;           // fl(z + fl(q-z)) bitwise
    ls += (double)dd * (double)dd;
  }
  #pragma unroll
  for (int off = 32; off; off >>= 1) ls += __shfl_xor(ls, off, 64);
  if (lane == 0) wsum[wave] = ls;
  __syncthreads();
  if (tid == 0) atomicAdd(loss, wsum[0] + wsum[1] + wsum[2] + wsum[3]);
}

// ---- k4: finalize loss -----------------------------------------------------
__global__ void k4_final(const double* __restrict__ loss, float* __restrict__ out) {
  float m = (float)(*loss / ((double)NROWS * (double)DIM));
  out[0] = m + 0.25f * m;
}

// ======================= fallback path (ws too small) =======================
__global__ void k0_zsq(const float* __restrict__ z, float* __restrict__ zsq,
                       unsigned long long* __restrict__ keys, double* __restrict__ loss) {
  const int wave = threadIdx.x >> 6, lane = threadIdx.x & 63;
  const int row = blockIdx.x * 4 + wave;
  const float* zr = z + (size_t)row * DIM;
  float s = 0.f;
  #pragma unroll
  for (int i = 0; i < DIM / 64; ++i) { float v = zr[lane + i * 64]; s = fmaf(v, v, s); }
  #pragma unroll
  for (int off = 32; off; off >>= 1) s += __shfl_xor(s, off, 64);
  if (lane == 0) zsq[row] = s;
  const int gid = blockIdx.x * 256 + threadIdx.x;
  if (gid < NROWS) keys[gid] = ~0ull;
  if (gid == 0) *loss = 0.0;
}

__global__ __launch_bounds__(256, 2) void k1_mfma(
    const float* __restrict__ z, const float* __restrict__ cb,
    const float* __restrict__ zsq, unsigned long long* __restrict__ keys) {
  __shared__ half_t Ah[TM * SA], Al[TM * SA], Bh[TC * SA], Bl[TC * SA];
  __shared__ float lzs[TM];
  __shared__ float redD[TM][2];
  __shared__ int   redI[TM][2];

  const int tid  = threadIdx.x;
  const int row0  = blockIdx.x * TM;
  const int code0 = blockIdx.y * TC;
  const int wave = tid >> 6, lane = tid & 63;
  const int wm = wave & 1, wn = wave >> 1;
  const int q = lane >> 4, l16 = lane & 15;

  if (tid < TM) lzs[tid] = zsq[row0 + tid];

  const int srow = tid >> 2;
  const int sko  = (tid & 3) * 8;

  f32x4 acc0[16], acc1[16];
  #pragma unroll
  for (int i = 0; i < 16; ++i) {
    acc0[i] = (f32x4){0.f, 0.f, 0.f, 0.f};
    acc1[i] = (f32x4){0.f, 0.f, 0.f, 0.f};
  }

  const float* zp = z  + (size_t)row0  * DIM;
  const float* bp = cb + (size_t)code0 * DIM;

  for (int kd = 0; kd < DIM; kd += 32) {
    __syncthreads();
    #pragma unroll
    for (int s = 0; s < 2; ++s) {
      const int r = srow + s * 64;
      const float* srca = zp + (size_t)r * DIM + kd + sko;
      float4 v0 = *(const float4*)srca;
      float4 v1 = *(const float4*)(srca + 4);
      float a[8] = {v0.x, v0.y, v0.z, v0.w, v1.x, v1.y, v1.z, v1.w};
      half8 hi, lo;
      #pragma unroll
      for (int j = 0; j < 8; ++j) {
        half_t h = (half_t)a[j];
        hi[j] = h;
        lo[j] = (half_t)((a[j] - (float)h) * 4096.f);
      }
      *(half8*)&Ah[r * SA + sko] = hi;
      *(half8*)&Al[r * SA + sko] = lo;
      const float* srcb = bp + (size_t)r * DIM + kd + sko;
      v0 = *(const float4*)srcb; v1 = *(const float4*)(srcb + 4);
      float b[8] = {v0.x, v0.y, v0.z, v0.w, v1.x, v1.y, v1.z, v1.w};
      #pragma unroll
      for (int j = 0; j < 8; ++j) {
        float bs = b[j] * 4096.f;
        half_t h = (half_t)bs;
        hi[j] = h;
        lo[j] = (half_t)((bs - (float)h) * 4096.f);
      }
      *(half8*)&Bh[r * SA + sko] = hi;
      *(half8*)&Bl[r * SA + sko] = lo;
    }
    __syncthreads();

    half8 fa_h[4], fa_l[4], fb_h[4], fb_l[4];
    #pragma unroll
    for (int t = 0; t < 4; ++t) {
      const int ar = (wm * 64 + t * 16 + l16) * SA + q * 8;
      fa_h[t] = *(const half8*)&Ah[ar];
      fa_l[t] = *(const half8*)&Al[ar];
      const int br = (wn * 64 + t * 16 + l16) * SA + q * 8;
      fb_h[t] = *(const half8*)&Bh[br];
      fb_l[t] = *(const half8*)&Bl[br];
    }
    #pragma unroll
    for (int tm = 0; tm < 4; ++tm)
      #pragma unroll
      for (int tn = 0; tn < 4; ++tn) {
        const int i = tm * 4 + tn;
        acc0[i] = __builtin_amdgcn_mfma_f32_16x16x32_f16(fa_h[tm], fb_h[tn], acc0[i], 0, 0, 0);
        acc1[i] = __builtin_amdgcn_mfma_f32_16x16x32_f16(fa_l[tm], fb_h[tn], acc1[i], 0, 0, 0);
        acc1[i] = __builtin_amdgcn_mfma_f32_16x16x32_f16(fa_h[tm], fb_l[tn], acc1[i], 0, 0, 0);
      }
  }

  const float c1 = 2.44140625e-4f;
  const float c2 = -4.8828125e-4f;
  #pragma unroll
  for (int tm = 0; tm < 4; ++tm) {
    #pragma unroll
    for (int reg = 0; reg < 4; ++reg) {
      const int row_b = wm * 64 + tm * 16 + q * 4 + reg;
      const float zs = lzs[row_b];
      float bd = FLT_MAX; int bi = 0x7fffffff;
      #pragma unroll
      for (int tn = 0; tn < 4; ++tn) {
        const int i = tm * 4 + tn;
        float v = fmaf(c1, acc1[i][reg], acc0[i][reg]);
        float d = fmaf(c2, v, zs);
        const int ci = code0 + wn * 64 + tn * 16 + l16;
        if (d < bd || (d == bd && ci < bi)) { bd = d; bi = ci; }
      }
      #pragma unroll
      for (int off = 8; off; off >>= 1) {
        float od = __shfl_xor(bd, off, 64);
        int   oi = __shfl_xor(bi, off, 64);
        if (od < bd || (od == bd && oi < bi)) { bd = od; bi = oi; }
      }
      if (l16 == 0) { redD[row_b][wn] = bd; redI[row_b][wn] = bi; }
    }
  }
  __syncthreads();
  if (tid < TM) {
    float d0 = redD[tid][0]; int i0 = redI[tid][0];
    float d1 = redD[tid][1]; int i1 = redI[tid][1];
    if (d1 < d0 || (d1 == d0 && i1 < i0)) { d0 = d1; i0 = i1; }
    unsigned long long key = ((unsigned long long)__float_as_uint(d0) << 32) | (unsigned int)i0;
    atomicMin(&keys[row0 + tid], key);
  }
}

__global__ void k2_codes(const unsigned long long* __restrict__ keys,
                         float* __restrict__ out_codes, int* __restrict__ codes_i) {
  const int r = blockIdx.x * 256 + threadIdx.x;
  const int idx = (int)(unsigned int)(keys[r] & 0xffffffffull);
  out_codes[r] = (float)idx;
  codes_i[r] = idx;
}

__global__ void k3_quant_loss(const float* __restrict__ z, const float* __restrict__ cb,
                              const int* __restrict__ codes, float* __restrict__ outq,
                              double* __restrict__ loss) {
  const int gid = blockIdx.x * blockDim.x + threadIdx.x;
  const int e0 = gid * 4;
  const int row = e0 / DIM;
  const int col = e0 - row * DIM;
  const int c = codes[row];
  const float4 zv = *(const float4*)(z + e0);
  const float4 qv = *(const float4*)(cb + (size_t)c * DIM + col);
  float d0 = qv.x - zv.x, d1 = qv.y - zv.y, d2 = qv.z - zv.z, d3 = qv.w - zv.w;
  float4 ov = { zv.x + d0, zv.y + d1, zv.z + d2, zv.w + d3 };
  *(float4*)(outq + e0) = ov;
  double s = (double)(d0 * d0) + (double)(d1 * d1) + (double)(d2 * d2) + (double)(d3 * d3);
  #pragma unroll
  for (int off = 32; off; off >>= 1) s += __shfl_xor(s, off, 64);
  __shared__ double wsum[4];
  const int wave = threadIdx.x >> 6, lane = threadIdx.x & 63;
  if (lane == 0) wsum[wave] = s;
  __syncthreads();
  if (threadIdx.x == 0) atomicAdd(loss, wsum[0] + wsum[1] + wsum[2] + wsum[3]);
}

extern "C" void kernel_launch(void* const* d_in, const int* in_sizes, int n_in,
                              void* d_out, int out_size, void* d_ws, size_t ws_size,
                              hipStream_t stream) {
  const float* z  = (const float*)d_in[0];
  const float* cb = (const float*)d_in[1];
  float* out = (float*)d_out;          // [codes 4096][q_ste 3145728][loss 1]
  char* ws = (char*)d_ws;
  float*  zsq = (float*)(ws + WS_ZSQ);
  unsigned int* runmin = (unsigned int*)(ws + WS_RUNMIN);
  int* cnt     = (int*)(ws + WS_CNT);
  int* codes_i = (int*)(ws + WS_CODESI);
  double* loss = (double*)(ws + WS_LOSS);
  int* list    = (int*)(ws + WS_LIST);
  unsigned long long* keys = (unsigned long long*)(ws + WS_LIST);

  if (ws_size >= WS_NEED) {
    half_t* Ahg = (half_t*)(ws + WS_AH);
    half_t* Bhg = (half_t*)(ws + WS_BH);
    dim3 g1s(NROWS / 256, KCODES / 256);
    k_convA<<<NROWS / 4, 256, 0, stream>>>(z, Ahg, zsq, runmin, cnt, loss);
    k_convB<<<(KCODES * DIM / 8 + 255) / 256, 256, 0, stream>>>(cb, Bhg, KCODES * DIM / 8);
    k1_s1<<<g1s, 512, 0, stream>>>(Ahg, Bhg, zsq, runmin, cnt, list);
    k_refine<<<NROWS, 256, 0, stream>>>(z, cb, zsq, cnt, list, out, out + NROWS, loss);
  } else {
    dim3 g1(NROWS / TM, KCODES / TC);
    k0_zsq<<<NROWS / 4, 256, 0, stream>>>(z, zsq, keys, loss);
    k1_mfma<<<g1, 256, 0, stream>>>(z, cb, zsq, keys);
    k2_codes<<<NROWS / 256, 256, 0, stream>>>(keys, out, codes_i);
    k3_quant_loss<<<(NROWS * DIM / 4) / 256, 256, 0, stream>>>(z, cb, codes_i, out + NROWS, loss);
  }

  k4_final<<<1, 1, 0, stream>>>(loss, out + NROWS + (size_t)NROWS * DIM);
}